// Round 1
// baseline (178.871 us; speedup 1.0000x reference)
//
#include <hip/hip_runtime.h>

#define D_MODEL 128
#define SEQ 2048
#define NH 4
#define DH 32
#define NBATCH 4
#define BHN (NBATCH * NH)   // 16

typedef __attribute__((ext_vector_type(8))) short bf16x8;
typedef __attribute__((ext_vector_type(4))) float f32x4;

static __device__ __forceinline__ unsigned short f2bf(float f) {
    union { float f; unsigned int u; } v; v.f = f;
    unsigned int r = v.u + 0x7FFFu + ((v.u >> 16) & 1u);  // RNE
    return (unsigned short)(r >> 16);
}

// ---------------- Kernel 1: LayerNorm + QKV projection -------------------
// 512 blocks x 256 threads; block handles 16 rows. Weights reused across the
// 16 rows from registers (one W element per d-iteration per thread) so L2
// weight traffic is 512*192KB = 98MB instead of 1.5GB.
__global__ __launch_bounds__(256) void k1_ln_qkv(
    const float* __restrict__ x,
    const float* __restrict__ Wq, const float* __restrict__ bq,
    const float* __restrict__ Wk, const float* __restrict__ bk,
    const float* __restrict__ Wv, const float* __restrict__ bv,
    const float* __restrict__ gamma, const float* __restrict__ beta,
    unsigned short* __restrict__ q_ws, unsigned short* __restrict__ k_ws,
    unsigned short* __restrict__ vt_ws)
{
    __shared__ float xn_sh[D_MODEL][16];   // transposed [d][row] for b128 reads
    const int t = threadIdx.x;
    const int wave = t >> 6, lane = t & 63;
    const int row0 = blockIdx.x * 16;

    // LN: wave w handles rows 4w..4w+3; lane covers d = lane, lane+64.
    for (int i = 0; i < 4; ++i) {
        int r = wave * 4 + i;
        const float* xr = x + (long)(row0 + r) * D_MODEL;
        float x0 = xr[lane], x1 = xr[lane + 64];
        float s = x0 + x1, s2 = x0 * x0 + x1 * x1;
        #pragma unroll
        for (int off = 32; off > 0; off >>= 1) {
            s  += __shfl_xor(s, off);
            s2 += __shfl_xor(s2, off);
        }
        float mu  = s * (1.0f / 128.0f);
        float var = s2 * (1.0f / 128.0f) - mu * mu;
        float rs  = rsqrtf(var + 1e-6f);
        xn_sh[lane][r]      = (x0 - mu) * rs * gamma[lane] + beta[lane];
        xn_sh[lane + 64][r] = (x1 - mu) * rs * gamma[lane + 64] + beta[lane + 64];
    }
    __syncthreads();

    const int c = t & 127;   // output column
    const int g = t >> 7;    // row group: rows g*8..g*8+7
    float aq[8], ak[8], av[8];
    #pragma unroll
    for (int r = 0; r < 8; ++r) { aq[r] = 0.f; ak[r] = 0.f; av[r] = 0.f; }

    for (int d = 0; d < D_MODEL; ++d) {
        float wq = Wq[d * D_MODEL + c];
        float wk = Wk[d * D_MODEL + c];
        float wv = Wv[d * D_MODEL + c];
        const float* xs = &xn_sh[d][g * 8];
        #pragma unroll
        for (int r = 0; r < 8; ++r) {
            float xv = xs[r];
            aq[r] += xv * wq; ak[r] += xv * wk; av[r] += xv * wv;
        }
    }

    // scores computed in exp2-domain: fold log2(e)/sqrt(Dh) into Q
    const float QSCALE = 0.17677669529663687f * 1.4426950408889634f;
    float bqv = bq[c], bkv = bk[c], bvv = bv[c];
    int h = c >> 5, dh = c & 31;
    #pragma unroll
    for (int r = 0; r < 8; ++r) {
        int row  = row0 + g * 8 + r;
        int b    = row >> 11;            // /SEQ
        int sIdx = row & (SEQ - 1);
        int bh   = b * NH + h;
        q_ws[(bh * SEQ + sIdx) * DH + dh] = f2bf((aq[r] + bqv) * QSCALE);
        k_ws[(bh * SEQ + sIdx) * DH + dh] = f2bf(ak[r] + bkv);
        vt_ws[(bh * DH + dh) * SEQ + sIdx] = f2bf(av[r] + bvv);  // V transposed
    }
}

// ---------------- Kernel 2: flash attention ------------------------------
// grid (32, 16), 256 threads = 4 waves; wave owns one 16-query tile, loops
// keys in steps of 32. Layouts (verified m89/m120):
//   A-frag: A[m=lane&15][k=quad*8+j]   B-frag: B[k=quad*8+j][n=lane&15]
//   C-frag: row=quad*4+reg, col=lane&15
__global__ __launch_bounds__(256) void k2_attn(
    const unsigned short* __restrict__ q_ws,
    const unsigned short* __restrict__ k_ws,
    const unsigned short* __restrict__ vt_ws,
    float* __restrict__ ctx_ws)
{
    __shared__ __align__(16) unsigned short p_sh[4][16][32];  // per-wave P tile
    const int wave = threadIdx.x >> 6, lane = threadIdx.x & 63;
    const int bh = blockIdx.y;
    const int q0 = (blockIdx.x * 4 + wave) * 16;
    const int col = lane & 15, quad = lane >> 4;

    // Q A-frag: Q[q0+col][quad*8+j] — contiguous 16B
    bf16x8 qfrag = *(const bf16x8*)(q_ws + (bh * SEQ + q0 + col) * DH + quad * 8);

    const unsigned short* kb_ptr = k_ws + bh * SEQ * DH;
    const unsigned short* vb_ptr = vt_ws + bh * DH * SEQ;

    f32x4 ctx0 = {0.f, 0.f, 0.f, 0.f}, ctx1 = {0.f, 0.f, 0.f, 0.f};
    float m[4], l[4];
    #pragma unroll
    for (int r = 0; r < 4; ++r) { m[r] = -INFINITY; l[r] = 0.f; }

    for (int kb = 0; kb < SEQ; kb += 32) {
        // B-frag = K^T: B[d][key] = K[key][d] -> lane reads K[kb+col][quad*8+j]
        bf16x8 kf0 = *(const bf16x8*)(kb_ptr + (kb + col) * DH + quad * 8);
        bf16x8 kf1 = *(const bf16x8*)(kb_ptr + (kb + 16 + col) * DH + quad * 8);
        f32x4 z = {0.f, 0.f, 0.f, 0.f};
        f32x4 s0 = __builtin_amdgcn_mfma_f32_16x16x32_bf16(qfrag, kf0, z, 0, 0, 0);
        f32x4 s1 = __builtin_amdgcn_mfma_f32_16x16x32_bf16(qfrag, kf1, z, 0, 0, 0);

        #pragma unroll
        for (int r = 0; r < 4; ++r) {
            // row = q0 + quad*4 + r ; this lane holds cols col and col+16
            float mt = fmaxf(s0[r], s1[r]);
            mt = fmaxf(mt, __shfl_xor(mt, 1));
            mt = fmaxf(mt, __shfl_xor(mt, 2));
            mt = fmaxf(mt, __shfl_xor(mt, 4));
            mt = fmaxf(mt, __shfl_xor(mt, 8));
            float mn = fmaxf(m[r], mt);
            float alpha = exp2f(m[r] - mn);
            m[r] = mn;
            float p0 = exp2f(s0[r] - mn);
            float p1 = exp2f(s1[r] - mn);
            float lt = p0 + p1;
            lt += __shfl_xor(lt, 1);
            lt += __shfl_xor(lt, 2);
            lt += __shfl_xor(lt, 4);
            lt += __shfl_xor(lt, 8);
            l[r] = l[r] * alpha + lt;
            ctx0[r] *= alpha;
            ctx1[r] *= alpha;
            p_sh[wave][quad * 4 + r][col]      = f2bf(p0);
            p_sh[wave][quad * 4 + r][col + 16] = f2bf(p1);
        }
        // C-layout -> A-layout via per-wave LDS round trip (in-order DS ops,
        // no cross-wave sharing => no barrier needed)
        bf16x8 pf  = *(const bf16x8*)&p_sh[wave][col][quad * 8];
        // B-frag = V: B[key][dh] -> lane reads Vt[dh=col(+16)][kb+quad*8+j]
        bf16x8 vf0 = *(const bf16x8*)(vb_ptr + col * SEQ + kb + quad * 8);
        bf16x8 vf1 = *(const bf16x8*)(vb_ptr + (col + 16) * SEQ + kb + quad * 8);
        ctx0 = __builtin_amdgcn_mfma_f32_16x16x32_bf16(pf, vf0, ctx0, 0, 0, 0);
        ctx1 = __builtin_amdgcn_mfma_f32_16x16x32_bf16(pf, vf1, ctx1, 0, 0, 0);
    }

    const int b = bh >> 2, h = bh & 3;
    #pragma unroll
    for (int r = 0; r < 4; ++r) {
        float inv = 1.0f / l[r];
        int srow = q0 + quad * 4 + r;
        float* o = ctx_ws + (long)(b * SEQ + srow) * D_MODEL + h * DH;
        o[col]      = ctx0[r] * inv;
        o[col + 16] = ctx1[r] * inv;
    }
}

// ---------------- Kernel 3: output projection + residual -----------------
__global__ __launch_bounds__(256) void k3_out(
    const float* __restrict__ ctx_ws, const float* __restrict__ Wo,
    const float* __restrict__ bo, const float* __restrict__ x,
    float* __restrict__ out)
{
    __shared__ float c_sh[D_MODEL][16];
    const int t = threadIdx.x;
    const int row0 = blockIdx.x * 16;
    #pragma unroll
    for (int i = 0; i < 8; ++i) {
        int linear = t + i * 256;            // 0..2047
        int r = linear >> 7, cc = linear & 127;
        c_sh[cc][r] = ctx_ws[(long)(row0 + r) * D_MODEL + cc];
    }
    __syncthreads();

    const int c = t & 127, g = t >> 7;
    float acc[8];
    #pragma unroll
    for (int r = 0; r < 8; ++r) acc[r] = 0.f;
    for (int d = 0; d < D_MODEL; ++d) {
        float w = Wo[d * D_MODEL + c];
        const float* cs = &c_sh[d][g * 8];
        #pragma unroll
        for (int r = 0; r < 8; ++r) acc[r] += cs[r] * w;
    }
    float bv = bo[c];
    #pragma unroll
    for (int r = 0; r < 8; ++r) {
        long row = row0 + g * 8 + r;
        out[row * D_MODEL + c] = acc[r] + bv + x[row * D_MODEL + c];
    }
}

extern "C" void kernel_launch(void* const* d_in, const int* in_sizes, int n_in,
                              void* d_out, int out_size, void* d_ws, size_t ws_size,
                              hipStream_t stream) {
    const float* x     = (const float*)d_in[0];
    const float* Wq    = (const float*)d_in[1];
    const float* bq    = (const float*)d_in[2];
    const float* Wk    = (const float*)d_in[3];
    const float* bk    = (const float*)d_in[4];
    const float* Wv    = (const float*)d_in[5];
    const float* bv    = (const float*)d_in[6];
    const float* gamma = (const float*)d_in[7];
    const float* beta  = (const float*)d_in[8];
    const float* Wo    = (const float*)d_in[9];
    const float* bo    = (const float*)d_in[10];
    float* out = (float*)d_out;

    const size_t QKV_ELEMS = (size_t)BHN * SEQ * DH;      // 1,048,576
    unsigned short* q_ws  = (unsigned short*)d_ws;
    unsigned short* k_ws  = q_ws + QKV_ELEMS;
    unsigned short* vt_ws = k_ws + QKV_ELEMS;
    float* ctx_ws = (float*)(vt_ws + QKV_ELEMS);          // 4MB; total 10MB

    k1_ln_qkv<<<dim3(NBATCH * SEQ / 16), 256, 0, stream>>>(
        x, Wq, bq, Wk, bk, Wv, bv, gamma, beta, q_ws, k_ws, vt_ws);
    k2_attn<<<dim3(SEQ / 64, BHN), 256, 0, stream>>>(q_ws, k_ws, vt_ws, ctx_ws);
    k3_out<<<dim3(NBATCH * SEQ / 16), 256, 0, stream>>>(ctx_ws, Wo, bo, x, out);
}

// Round 2
// 130.053 us; speedup vs baseline: 1.3754x; 1.3754x over previous
//
#include <hip/hip_runtime.h>

#define D_MODEL 128
#define SEQ 2048
#define NH 4
#define DH 32
#define NBATCH 4
#define BHN 16

typedef __attribute__((ext_vector_type(8))) short bf16x8;
typedef __attribute__((ext_vector_type(4))) float f32x4;
typedef __attribute__((ext_vector_type(4))) unsigned short u16x4;
typedef __attribute__((ext_vector_type(8))) unsigned short u16x8;

#define QSCALE (0.17677669529663687f * 1.4426950408889634f)  // log2e/sqrt(32)

static __device__ __forceinline__ unsigned short f2bf_rne(float f) {
    union { float f; unsigned int u; } v; v.f = f;
    unsigned int r = v.u + 0x7FFFu + ((v.u >> 16) & 1u);
    return (unsigned short)(r >> 16);
}

// ---- k0: transpose+cast weights to bf16. wt[512][128]: rows 0-127 = Wq
// out-cols, 128-255 Wk, 256-383 Wv, 384-511 Wo. wt[n][d] = W[d][n].
__global__ __launch_bounds__(256) void k0_prep(
    const float* __restrict__ Wq, const float* __restrict__ Wk,
    const float* __restrict__ Wv, const float* __restrict__ Wo,
    unsigned short* __restrict__ wt)
{
    __shared__ float tile[32][33];
    const int t = threadIdx.x;
    const int tile_n = blockIdx.x >> 2, tile_d = blockIdx.x & 3;
    const float* W = (tile_n < 4) ? Wq : (tile_n < 8) ? Wk : (tile_n < 12) ? Wv : Wo;
    const int ncol0 = (tile_n & 3) * 32;
    #pragma unroll
    for (int i = 0; i < 4; ++i) {
        int dd = (t >> 5) + i * 8, nn = t & 31;
        tile[dd][nn] = W[(tile_d * 32 + dd) * 128 + ncol0 + nn];
    }
    __syncthreads();
    #pragma unroll
    for (int i = 0; i < 4; ++i) {
        int nn = (t >> 5) + i * 8, dd = t & 31;
        wt[(tile_n * 32 + nn) * 128 + tile_d * 32 + dd] = f2bf_rne(tile[dd][nn]);
    }
}

// ---- k1: LayerNorm -> bf16 -> MFMA QKV projection. 256 blocks x 32 rows.
// Waves: (w&1) -> 16-row strip, (w>>1) -> half of the 24 col-tiles.
__global__ __launch_bounds__(256) void k1_ln_qkv(
    const float* __restrict__ x, const unsigned short* __restrict__ wt,
    const float* __restrict__ bq, const float* __restrict__ bk,
    const float* __restrict__ bv,
    const float* __restrict__ gamma, const float* __restrict__ beta,
    unsigned short* __restrict__ q_ws, unsigned short* __restrict__ k_ws,
    unsigned short* __restrict__ vt_ws)
{
    __shared__ __align__(16) unsigned short xsh[32][136];  // pad: stride 272B (16B-aligned)
    const int t = threadIdx.x, w = t >> 6, lane = t & 63;
    const int row0 = blockIdx.x * 32;
    const float g0 = gamma[lane], g1 = gamma[lane + 64];
    const float be0 = beta[lane], be1 = beta[lane + 64];
    #pragma unroll
    for (int i = 0; i < 8; ++i) {
        int r = w * 8 + i;
        const float* xr = x + (size_t)(row0 + r) * 128;
        float x0 = xr[lane], x1 = xr[lane + 64];
        float s = x0 + x1, s2 = x0 * x0 + x1 * x1;
        #pragma unroll
        for (int off = 32; off > 0; off >>= 1) {
            s += __shfl_xor(s, off);
            s2 += __shfl_xor(s2, off);
        }
        float mu  = s * (1.0f / 128.0f);
        float var = s2 * (1.0f / 128.0f) - mu * mu;
        float rs  = rsqrtf(var + 1e-6f);
        xsh[r][lane]      = f2bf_rne((x0 - mu) * rs * g0 + be0);
        xsh[r][lane + 64] = f2bf_rne((x1 - mu) * rs * g1 + be1);
    }
    __syncthreads();

    const int col = lane & 15, quad = lane >> 4;
    const int mrow0 = (w & 1) * 16;
    const int nt0 = (w >> 1) * 12;
    bf16x8 a[4];
    #pragma unroll
    for (int kk = 0; kk < 4; ++kk)
        a[kk] = *(const bf16x8*)&xsh[mrow0 + col][kk * 32 + quad * 8];

    const int b = row0 >> 11;
    const int sloc0 = (row0 & (SEQ - 1)) + mrow0 + quad * 4;

    for (int nt = nt0; nt < nt0 + 12; ++nt) {
        int n = nt * 16 + col;  // 0..383
        const unsigned short* wrow = wt + n * 128;
        f32x4 c = {0.f, 0.f, 0.f, 0.f};
        #pragma unroll
        for (int kk = 0; kk < 4; ++kk) {
            bf16x8 bf = *(const bf16x8*)(wrow + kk * 32 + quad * 8);
            c = __builtin_amdgcn_mfma_f32_16x16x32_bf16(a[kk], bf, c, 0, 0, 0);
        }
        int m = nt >> 3;  // 0=q 1=k 2=v (wave-uniform)
        int nn = n & 127, h = nn >> 5, dh = nn & 31, bh = b * NH + h;
        if (m == 0) {
            float bias = bq[nn];
            #pragma unroll
            for (int r = 0; r < 4; ++r)
                q_ws[(size_t)(bh * SEQ + sloc0 + r) * DH + dh] =
                    f2bf_rne((c[r] + bias) * QSCALE);
        } else if (m == 1) {
            float bias = bk[nn];
            #pragma unroll
            for (int r = 0; r < 4; ++r)
                k_ws[(size_t)(bh * SEQ + sloc0 + r) * DH + dh] = f2bf_rne(c[r] + bias);
        } else {
            float bias = bv[nn];
            u16x4 pv;
            #pragma unroll
            for (int r = 0; r < 4; ++r) pv[r] = f2bf_rne(c[r] + bias);
            *(u16x4*)(vt_ws + (size_t)(bh * DH + dh) * SEQ + sloc0) = pv;  // V^T, 8B store
        }
    }
}

// ---- k2: attention, unnormalized exp2-softmax (no online max).
// grid (32,16), 4 waves/block: wave = (tq = w>>1 query 32-tile, hf = w&1 key half).
// Even/odd key split across the two QK MFMAs => P pair packs into one u32,
// V stays in natural order. Partials combine linearly in LDS at the end.
__global__ __launch_bounds__(256) void k2_attn(
    const unsigned short* __restrict__ q_ws,
    const unsigned short* __restrict__ k_ws,
    const unsigned short* __restrict__ vt_ws,
    unsigned short* __restrict__ ctx_ws)
{
    __shared__ __align__(16) unsigned int p_sh[4][32][36];  // stride 36 u32: conflict-free, 16B-aligned
    __shared__ __align__(16) float comb[2][2][32][32];
    __shared__ float lsh[2][2][32];
    const int w = threadIdx.x >> 6, lane = threadIdx.x & 63;
    const int col = lane & 15, quad = lane >> 4;
    const int tq = w >> 1, hf = w & 1;
    const int bh = blockIdx.y;
    const int q0 = blockIdx.x * 64 + tq * 32;
    const unsigned short* qb  = q_ws  + (size_t)bh * SEQ * DH;
    const unsigned short* kbp = k_ws  + (size_t)bh * SEQ * DH;
    const unsigned short* vbp = vt_ws + (size_t)bh * DH * SEQ;

    bf16x8 qf0 = *(const bf16x8*)(qb + (q0 + col) * DH + quad * 8);
    bf16x8 qf1 = *(const bf16x8*)(qb + (q0 + 16 + col) * DH + quad * 8);

    f32x4 c00 = {0.f,0.f,0.f,0.f}, c01 = {0.f,0.f,0.f,0.f};
    f32x4 c10 = {0.f,0.f,0.f,0.f}, c11 = {0.f,0.f,0.f,0.f};
    float l0[4] = {0.f,0.f,0.f,0.f}, l1[4] = {0.f,0.f,0.f,0.f};

    for (int it = 0; it < 32; ++it) {
        int kb = hf * 1024 + it * 32;
        // K B-frags: kf0 = even keys kb+2c, kf1 = odd keys kb+2c+1
        bf16x8 kf0 = *(const bf16x8*)(kbp + (kb + 2 * col) * DH + quad * 8);
        bf16x8 kf1 = *(const bf16x8*)(kbp + (kb + 2 * col + 1) * DH + quad * 8);
        bf16x8 vf0 = *(const bf16x8*)(vbp + (size_t)col * SEQ + kb + quad * 8);
        bf16x8 vf1 = *(const bf16x8*)(vbp + (size_t)(16 + col) * SEQ + kb + quad * 8);
        f32x4 z = {0.f,0.f,0.f,0.f};
        f32x4 s00 = __builtin_amdgcn_mfma_f32_16x16x32_bf16(qf0, kf0, z, 0, 0, 0);
        f32x4 s01 = __builtin_amdgcn_mfma_f32_16x16x32_bf16(qf0, kf1, z, 0, 0, 0);
        f32x4 s10 = __builtin_amdgcn_mfma_f32_16x16x32_bf16(qf1, kf0, z, 0, 0, 0);
        f32x4 s11 = __builtin_amdgcn_mfma_f32_16x16x32_bf16(qf1, kf1, z, 0, 0, 0);
        #pragma unroll
        for (int r = 0; r < 4; ++r) {
            float p00 = exp2f(s00[r]), p01 = exp2f(s01[r]);
            l0[r] += p00 + p01;
            p_sh[w][quad * 4 + r][col] =
                (__float_as_uint(p00) >> 16) | (__float_as_uint(p01) & 0xFFFF0000u);
            float p10 = exp2f(s10[r]), p11 = exp2f(s11[r]);
            l1[r] += p10 + p11;
            p_sh[w][16 + quad * 4 + r][col] =
                (__float_as_uint(p10) >> 16) | (__float_as_uint(p11) & 0xFFFF0000u);
        }
        bf16x8 pf0 = *(const bf16x8*)&p_sh[w][col][quad * 4];
        bf16x8 pf1 = *(const bf16x8*)&p_sh[w][16 + col][quad * 4];
        c00 = __builtin_amdgcn_mfma_f32_16x16x32_bf16(pf0, vf0, c00, 0, 0, 0);
        c01 = __builtin_amdgcn_mfma_f32_16x16x32_bf16(pf0, vf1, c01, 0, 0, 0);
        c10 = __builtin_amdgcn_mfma_f32_16x16x32_bf16(pf1, vf0, c10, 0, 0, 0);
        c11 = __builtin_amdgcn_mfma_f32_16x16x32_bf16(pf1, vf1, c11, 0, 0, 0);
    }

    #pragma unroll
    for (int r = 0; r < 4; ++r) {
        #pragma unroll
        for (int off = 1; off < 16; off <<= 1) {
            l0[r] += __shfl_xor(l0[r], off);
            l1[r] += __shfl_xor(l1[r], off);
        }
    }
    #pragma unroll
    for (int r = 0; r < 4; ++r) {
        int rr = quad * 4 + r;
        comb[tq][hf][rr][col]           = c00[r];
        comb[tq][hf][rr][16 + col]      = c01[r];
        comb[tq][hf][16 + rr][col]      = c10[r];
        comb[tq][hf][16 + rr][16 + col] = c11[r];
    }
    if (col == 0) {
        #pragma unroll
        for (int r = 0; r < 4; ++r) {
            lsh[tq][hf][quad * 4 + r]      = l0[r];
            lsh[tq][hf][16 + quad * 4 + r] = l1[r];
        }
    }
    __syncthreads();
    {
        int t_ = threadIdx.x >> 7;
        int row = (threadIdx.x >> 2) & 31;
        int cg = threadIdx.x & 3;
        float linv = 1.0f / (lsh[t_][0][row] + lsh[t_][1][row]);
        u16x8 ov;
        #pragma unroll
        for (int j = 0; j < 8; ++j) {
            int cc = cg * 8 + j;
            ov[j] = f2bf_rne((comb[t_][0][row][cc] + comb[t_][1][row][cc]) * linv);
        }
        int s = blockIdx.x * 64 + t_ * 32 + row;
        int b = bh >> 2, h = bh & 3;
        *(u16x8*)(ctx_ws + (size_t)(b * SEQ + s) * 128 + h * 32 + cg * 8) = ov;
    }
}

// ---- k3: out = ctx @ Wo + bo + x. 256 blocks x 32 rows, MFMA.
__global__ __launch_bounds__(256) void k3_out(
    const unsigned short* __restrict__ ctx_ws,
    const unsigned short* __restrict__ wt_o, const float* __restrict__ bo,
    const float* __restrict__ x, float* __restrict__ out)
{
    const int t = threadIdx.x, w = t >> 6, lane = t & 63;
    const int col = lane & 15, quad = lane >> 4;
    const int row0 = blockIdx.x * 32 + (w & 1) * 16;
    bf16x8 a[4];
    #pragma unroll
    for (int kk = 0; kk < 4; ++kk)
        a[kk] = *(const bf16x8*)(ctx_ws + (size_t)(row0 + col) * 128 + kk * 32 + quad * 8);
    const int nt0 = (w >> 1) * 4;
    for (int nt = nt0; nt < nt0 + 4; ++nt) {
        int n = nt * 16 + col;
        f32x4 c = {0.f, 0.f, 0.f, 0.f};
        #pragma unroll
        for (int kk = 0; kk < 4; ++kk) {
            bf16x8 bf = *(const bf16x8*)(wt_o + n * 128 + kk * 32 + quad * 8);
            c = __builtin_amdgcn_mfma_f32_16x16x32_bf16(a[kk], bf, c, 0, 0, 0);
        }
        float bias = bo[n];
        #pragma unroll
        for (int r = 0; r < 4; ++r) {
            int srow = row0 + quad * 4 + r;
            out[(size_t)srow * 128 + n] = c[r] + bias + x[(size_t)srow * 128 + n];
        }
    }
}

extern "C" void kernel_launch(void* const* d_in, const int* in_sizes, int n_in,
                              void* d_out, int out_size, void* d_ws, size_t ws_size,
                              hipStream_t stream) {
    const float* x     = (const float*)d_in[0];
    const float* Wq    = (const float*)d_in[1];
    const float* bq    = (const float*)d_in[2];
    const float* Wk    = (const float*)d_in[3];
    const float* bk    = (const float*)d_in[4];
    const float* Wv    = (const float*)d_in[5];
    const float* bv    = (const float*)d_in[6];
    const float* gamma = (const float*)d_in[7];
    const float* beta  = (const float*)d_in[8];
    const float* Wo    = (const float*)d_in[9];
    const float* bo    = (const float*)d_in[10];
    float* out = (float*)d_out;

    const size_t QKV_ELEMS = (size_t)BHN * SEQ * DH;  // 1M
    unsigned short* q_ws   = (unsigned short*)d_ws;
    unsigned short* k_ws   = q_ws + QKV_ELEMS;
    unsigned short* vt_ws  = k_ws + QKV_ELEMS;
    unsigned short* ctx_ws = vt_ws + QKV_ELEMS;
    unsigned short* wt     = ctx_ws + QKV_ELEMS;      // [512][128] bf16
    unsigned short* wt_o   = wt + 384 * 128;

    k0_prep<<<64, 256, 0, stream>>>(Wq, Wk, Wv, Wo, wt);
    k1_ln_qkv<<<256, 256, 0, stream>>>(x, wt, bq, bk, bv, gamma, beta,
                                       q_ws, k_ws, vt_ws);
    k2_attn<<<dim3(SEQ / 64, BHN), 256, 0, stream>>>(q_ws, k_ws, vt_ws, ctx_ws);
    k3_out<<<256, 256, 0, stream>>>(ctx_ws, wt_o, bo, x, out);
}

// Round 3
// 117.564 us; speedup vs baseline: 1.5215x; 1.1062x over previous
//
#include <hip/hip_runtime.h>

#define D_MODEL 128
#define SEQ 2048
#define NH 4
#define DH 32
#define NBATCH 4
#define BHN 16

typedef __attribute__((ext_vector_type(8))) short bf16x8;
typedef __attribute__((ext_vector_type(4))) float f32x4;
typedef __attribute__((ext_vector_type(4))) unsigned short u16x4;
typedef __attribute__((ext_vector_type(8))) unsigned short u16x8;

#define QSCALE (0.17677669529663687f * 1.4426950408889634f)  // log2e/sqrt(32)

static __device__ __forceinline__ unsigned short f2bf_rne(float f) {
    union { float f; unsigned int u; } v; v.f = f;
    unsigned int r = v.u + 0x7FFFu + ((v.u >> 16) & 1u);
    return (unsigned short)(r >> 16);
}

// ======================= Fragment-major layouts ==========================
// All tensors are stored so that one wave's MFMA fragment load is one
// contiguous 1KB (64 lanes x 16B) block.
//
// Weights wf: 32 n-tiles (q:0-7, k:8-15, v:16-23, o:24-31) x 4 kk x 64 lanes
//   x 8 elems.  B-frag: B[k=kk*32+quad*8+j][n=nt*16+col], lane=quad*16+col.
// Q  qf_ws: [bh][qi(128)][lane][8]   A-frag: Q[qi*16+col][quad*8+j]
// K  kf_ws: [bh][kbi(64)][f(2)][lane][8]  B-frag f=0: even keys kb+2*col,
//   f=1: odd keys kb+2*col+1; k-dim d = quad*8+j.
// V  vf_ws: [bh][kbi(64)][f(2)][lane][8]  B-frag: V[kb+quad*8+j][d], f=0:
//   d=col, f=1: d=col+16.
// ctx ctx_f: [mt(512)][kk(4)][lane][8]  A-frag: ctx[mt*16+col][kk*32+quad*8+j]

// ---- k0: weights -> bf16 fragment-major (runs every call; 192KB, tiny)
__global__ __launch_bounds__(256) void k0_prep(
    const float* __restrict__ Wq, const float* __restrict__ Wk,
    const float* __restrict__ Wv, const float* __restrict__ Wo,
    unsigned short* __restrict__ wf)
{
    int tid = blockIdx.x * 256 + threadIdx.x;   // 0..8191
    int nt = tid >> 8, kk = (tid >> 6) & 3, lane = tid & 63;
    int col = lane & 15, quad = lane >> 4;
    const float* W = (nt < 8) ? Wq : (nt < 16) ? Wk : (nt < 24) ? Wv : Wo;
    int n = (nt & 7) * 16 + col;
    u16x8 v;
    #pragma unroll
    for (int j = 0; j < 8; ++j)
        v[j] = f2bf_rne(W[(kk * 32 + quad * 8 + j) * 128 + n]);
    *(u16x8*)(wf + (size_t)tid * 8) = v;
}

// ---- k1: LayerNorm -> bf16 -> MFMA QKV, frag-major outputs.
__global__ __launch_bounds__(256) void k1_ln_qkv(
    const float* __restrict__ x, const unsigned short* __restrict__ wf,
    const float* __restrict__ bq, const float* __restrict__ bk,
    const float* __restrict__ bv,
    const float* __restrict__ gamma, const float* __restrict__ beta,
    unsigned short* __restrict__ qf_ws, unsigned short* __restrict__ kf_ws,
    unsigned short* __restrict__ vf_ws)
{
    __shared__ __align__(16) unsigned short xsh[32][136];
    const int t = threadIdx.x, w = t >> 6, lane = t & 63;
    const int row0 = blockIdx.x * 32;
    const float g0 = gamma[lane], g1 = gamma[lane + 64];
    const float be0 = beta[lane], be1 = beta[lane + 64];
    #pragma unroll
    for (int i = 0; i < 8; ++i) {
        int r = w * 8 + i;
        const float* xr = x + (size_t)(row0 + r) * 128;
        float x0 = xr[lane], x1 = xr[lane + 64];
        float s = x0 + x1, s2 = x0 * x0 + x1 * x1;
        #pragma unroll
        for (int off = 32; off > 0; off >>= 1) {
            s += __shfl_xor(s, off);
            s2 += __shfl_xor(s2, off);
        }
        float mu  = s * (1.0f / 128.0f);
        float var = s2 * (1.0f / 128.0f) - mu * mu;
        float rs  = rsqrtf(var + 1e-6f);
        xsh[r][lane]      = f2bf_rne((x0 - mu) * rs * g0 + be0);
        xsh[r][lane + 64] = f2bf_rne((x1 - mu) * rs * g1 + be1);
    }
    __syncthreads();

    const int col = lane & 15, quad = lane >> 4;
    const int mrow0 = (w & 1) * 16;
    const int nt0 = (w >> 1) * 12;
    bf16x8 a[4];
    #pragma unroll
    for (int kk = 0; kk < 4; ++kk)
        a[kk] = *(const bf16x8*)&xsh[mrow0 + col][kk * 32 + quad * 8];

    const int row_g0 = row0 + mrow0 + quad * 4;     // global row of r=0
    const int b = row_g0 >> 11;
    const int s0 = row_g0 & (SEQ - 1);

    for (int nt = nt0; nt < nt0 + 12; ++nt) {
        int n = nt * 16 + col;
        const unsigned short* wrow = wf + (size_t)(nt * 4) * 512 + lane * 8;
        f32x4 c = {0.f, 0.f, 0.f, 0.f};
        #pragma unroll
        for (int kk = 0; kk < 4; ++kk) {
            bf16x8 bfr = *(const bf16x8*)(wrow + kk * 512);
            c = __builtin_amdgcn_mfma_f32_16x16x32_bf16(a[kk], bfr, c, 0, 0, 0);
        }
        int m = nt >> 3;                 // 0=q 1=k 2=v (wave-uniform)
        int nn = n & 127, h = nn >> 5, dh = nn & 31, bh = b * NH + h;
        if (m == 0) {
            float bias = bq[nn];
            #pragma unroll
            for (int r = 0; r < 4; ++r) {
                int s = s0 + r;
                size_t idx = ((size_t)(bh * 128 + (s >> 4)) * 64
                              + (dh >> 3) * 16 + (s & 15)) * 8 + (dh & 7);
                qf_ws[idx] = f2bf_rne((c[r] + bias) * QSCALE);
            }
        } else if (m == 1) {
            float bias = bk[nn];
            #pragma unroll
            for (int r = 0; r < 4; ++r) {
                int s = s0 + r;
                size_t idx = ((size_t)((bh * 64 + (s >> 5)) * 2 + (s & 1)) * 64
                              + (dh >> 3) * 16 + ((s & 31) >> 1)) * 8 + (dh & 7);
                kf_ws[idx] = f2bf_rne(c[r] + bias);
            }
        } else {
            float bias = bv[nn];
            u16x4 pv;
            #pragma unroll
            for (int r = 0; r < 4; ++r) pv[r] = f2bf_rne(c[r] + bias);
            size_t idx = ((size_t)((bh * 64 + (s0 >> 5)) * 2 + (dh >> 4)) * 64
                          + ((s0 & 31) >> 3) * 16 + (dh & 15)) * 8 + (s0 & 7);
            *(u16x4*)(vf_ws + idx) = pv;     // 4 consecutive keys -> 8B store
        }
    }
}

// ---- k2: attention, unnormalized exp2 softmax, frag-major I/O, prefetch.
// grid (32,16), waves (tq = w>>1 query 32-tile, hf = w&1 key half, 32 iters).
__global__ __launch_bounds__(256) void k2_attn(
    const unsigned short* __restrict__ qf_ws,
    const unsigned short* __restrict__ kf_ws,
    const unsigned short* __restrict__ vf_ws,
    unsigned short* __restrict__ ctx_f)
{
    __shared__ __align__(16) unsigned int p_sh[4][32][36];
    __shared__ __align__(16) float comb[2][2][32][33];   // pad 33: no conflicts
    __shared__ float lsh[2][2][32];
    const int w = threadIdx.x >> 6, lane = threadIdx.x & 63;
    const int col = lane & 15, quad = lane >> 4;
    const int tq = w >> 1, hf = w & 1;
    const int bh = blockIdx.y;
    const int qi = blockIdx.x * 4 + tq * 2;

    const unsigned short* qb = qf_ws + ((size_t)(bh * 128 + qi)) * 512;
    const unsigned short* kb = kf_ws + (size_t)bh * 65536;
    const unsigned short* vb = vf_ws + (size_t)bh * 65536;

    bf16x8 qf0 = *(const bf16x8*)(qb + lane * 8);
    bf16x8 qf1 = *(const bf16x8*)(qb + 512 + lane * 8);

    f32x4 c00 = {0.f,0.f,0.f,0.f}, c01 = {0.f,0.f,0.f,0.f};
    f32x4 c10 = {0.f,0.f,0.f,0.f}, c11 = {0.f,0.f,0.f,0.f};
    float l0[4] = {0.f,0.f,0.f,0.f}, l1[4] = {0.f,0.f,0.f,0.f};

    const int kbi0 = hf * 32;
    // prefetch iteration 0
    bf16x8 kf0 = *(const bf16x8*)(kb + (size_t)kbi0 * 1024 + lane * 8);
    bf16x8 kf1 = *(const bf16x8*)(kb + (size_t)kbi0 * 1024 + 512 + lane * 8);
    bf16x8 vf0 = *(const bf16x8*)(vb + (size_t)kbi0 * 1024 + lane * 8);
    bf16x8 vf1 = *(const bf16x8*)(vb + (size_t)kbi0 * 1024 + 512 + lane * 8);

    for (int it = 0; it < 32; ++it) {
        int nkbi = kbi0 + ((it + 1) & 31);
        bf16x8 nkf0 = *(const bf16x8*)(kb + (size_t)nkbi * 1024 + lane * 8);
        bf16x8 nkf1 = *(const bf16x8*)(kb + (size_t)nkbi * 1024 + 512 + lane * 8);
        bf16x8 nvf0 = *(const bf16x8*)(vb + (size_t)nkbi * 1024 + lane * 8);
        bf16x8 nvf1 = *(const bf16x8*)(vb + (size_t)nkbi * 1024 + 512 + lane * 8);

        f32x4 z = {0.f,0.f,0.f,0.f};
        f32x4 s00 = __builtin_amdgcn_mfma_f32_16x16x32_bf16(qf0, kf0, z, 0, 0, 0);
        f32x4 s01 = __builtin_amdgcn_mfma_f32_16x16x32_bf16(qf0, kf1, z, 0, 0, 0);
        f32x4 s10 = __builtin_amdgcn_mfma_f32_16x16x32_bf16(qf1, kf0, z, 0, 0, 0);
        f32x4 s11 = __builtin_amdgcn_mfma_f32_16x16x32_bf16(qf1, kf1, z, 0, 0, 0);
        #pragma unroll
        for (int r = 0; r < 4; ++r) {
            float p00 = __builtin_amdgcn_exp2f(s00[r]);
            float p01 = __builtin_amdgcn_exp2f(s01[r]);
            l0[r] += p00 + p01;
            p_sh[w][quad * 4 + r][col] =
                (__float_as_uint(p00) >> 16) | (__float_as_uint(p01) & 0xFFFF0000u);
            float p10 = __builtin_amdgcn_exp2f(s10[r]);
            float p11 = __builtin_amdgcn_exp2f(s11[r]);
            l1[r] += p10 + p11;
            p_sh[w][16 + quad * 4 + r][col] =
                (__float_as_uint(p10) >> 16) | (__float_as_uint(p11) & 0xFFFF0000u);
        }
        bf16x8 pf0 = *(const bf16x8*)&p_sh[w][col][quad * 4];
        bf16x8 pf1 = *(const bf16x8*)&p_sh[w][16 + col][quad * 4];
        c00 = __builtin_amdgcn_mfma_f32_16x16x32_bf16(pf0, vf0, c00, 0, 0, 0);
        c01 = __builtin_amdgcn_mfma_f32_16x16x32_bf16(pf0, vf1, c01, 0, 0, 0);
        c10 = __builtin_amdgcn_mfma_f32_16x16x32_bf16(pf1, vf0, c10, 0, 0, 0);
        c11 = __builtin_amdgcn_mfma_f32_16x16x32_bf16(pf1, vf1, c11, 0, 0, 0);
        kf0 = nkf0; kf1 = nkf1; vf0 = nvf0; vf1 = nvf1;
    }

    #pragma unroll
    for (int r = 0; r < 4; ++r) {
        #pragma unroll
        for (int off = 1; off < 16; off <<= 1) {
            l0[r] += __shfl_xor(l0[r], off);
            l1[r] += __shfl_xor(l1[r], off);
        }
    }
    #pragma unroll
    for (int r = 0; r < 4; ++r) {
        int rr = quad * 4 + r;
        comb[tq][hf][rr][col]           = c00[r];
        comb[tq][hf][rr][16 + col]      = c01[r];
        comb[tq][hf][16 + rr][col]      = c10[r];
        comb[tq][hf][16 + rr][16 + col] = c11[r];
    }
    if (col == 0) {
        #pragma unroll
        for (int r = 0; r < 4; ++r) {
            lsh[tq][hf][quad * 4 + r]      = l0[r];
            lsh[tq][hf][16 + quad * 4 + r] = l1[r];
        }
    }
    __syncthreads();
    {
        int t_ = threadIdx.x >> 7;
        int row = (threadIdx.x >> 2) & 31;
        int cg = threadIdx.x & 3;
        float linv = 1.0f / (lsh[t_][0][row] + lsh[t_][1][row]);
        u16x8 ov;
        #pragma unroll
        for (int j = 0; j < 8; ++j) {
            int cc = cg * 8 + j;
            ov[j] = f2bf_rne((comb[t_][0][row][cc] + comb[t_][1][row][cc]) * linv);
        }
        int s_loc = blockIdx.x * 64 + t_ * 32 + row;
        int b = bh >> 2, h = bh & 3;
        int s_g = b * SEQ + s_loc;
        size_t idx = ((size_t)((s_g >> 4) * 4 + h) * 64 + cg * 16 + (s_g & 15)) * 8;
        *(u16x8*)(ctx_f + idx) = ov;    // frag-major, coalesced 16B stores
    }
}

// ---- k3: out = ctx @ Wo + bo + x, frag-major inputs.
__global__ __launch_bounds__(256) void k3_out(
    const unsigned short* __restrict__ ctx_f,
    const unsigned short* __restrict__ wf, const float* __restrict__ bo,
    const float* __restrict__ x, float* __restrict__ out)
{
    const int t = threadIdx.x, w = t >> 6, lane = t & 63;
    const int col = lane & 15, quad = lane >> 4;
    const int mt = blockIdx.x * 2 + (w & 1);
    bf16x8 a[4];
    #pragma unroll
    for (int kk = 0; kk < 4; ++kk)
        a[kk] = *(const bf16x8*)(ctx_f + ((size_t)(mt * 4 + kk) * 64 + lane) * 8);
    for (int i = 0; i < 4; ++i) {
        int ntl = (w >> 1) * 4 + i;          // 0..7 within Wo
        int nt_g = 24 + ntl;
        int n = ntl * 16 + col;
        f32x4 c = {0.f, 0.f, 0.f, 0.f};
        #pragma unroll
        for (int kk = 0; kk < 4; ++kk) {
            bf16x8 bfr = *(const bf16x8*)(wf + ((size_t)(nt_g * 4 + kk) * 64 + lane) * 8);
            c = __builtin_amdgcn_mfma_f32_16x16x32_bf16(a[kk], bfr, c, 0, 0, 0);
        }
        float bias = bo[n];
        #pragma unroll
        for (int r = 0; r < 4; ++r) {
            size_t row_g = (size_t)mt * 16 + quad * 4 + r;
            out[row_g * 128 + n] = c[r] + bias + x[row_g * 128 + n];
        }
    }
}

extern "C" void kernel_launch(void* const* d_in, const int* in_sizes, int n_in,
                              void* d_out, int out_size, void* d_ws, size_t ws_size,
                              hipStream_t stream) {
    const float* x     = (const float*)d_in[0];
    const float* Wq    = (const float*)d_in[1];
    const float* bq    = (const float*)d_in[2];
    const float* Wk    = (const float*)d_in[3];
    const float* bk    = (const float*)d_in[4];
    const float* Wv    = (const float*)d_in[5];
    const float* bv    = (const float*)d_in[6];
    const float* gamma = (const float*)d_in[7];
    const float* beta  = (const float*)d_in[8];
    const float* Wo    = (const float*)d_in[9];
    const float* bo    = (const float*)d_in[10];
    float* out = (float*)d_out;

    const size_t QKV_ELEMS = (size_t)BHN * SEQ * DH;  // 1M
    unsigned short* qf_ws = (unsigned short*)d_ws;
    unsigned short* kf_ws = qf_ws + QKV_ELEMS;
    unsigned short* vf_ws = kf_ws + QKV_ELEMS;
    unsigned short* ctx_f = vf_ws + QKV_ELEMS;
    unsigned short* wf    = ctx_f + QKV_ELEMS;        // 512*128 bf16 frag-major

    k0_prep<<<32, 256, 0, stream>>>(Wq, Wk, Wv, Wo, wf);
    k1_ln_qkv<<<256, 256, 0, stream>>>(x, wf, bq, bk, bv, gamma, beta,
                                       qf_ws, kf_ws, vf_ws);
    k2_attn<<<dim3(SEQ / 64, BHN), 256, 0, stream>>>(qf_ws, kf_ws, vf_ws, ctx_f);
    k3_out<<<256, 256, 0, stream>>>(ctx_f, wf, bo, x, out);
}

// Round 4
// 108.700 us; speedup vs baseline: 1.6455x; 1.0815x over previous
//
#include <hip/hip_runtime.h>

#define D_MODEL 128
#define SEQ 2048
#define NH 4
#define DH 32
#define NBATCH 4
#define BHN 16

typedef __attribute__((ext_vector_type(8))) short bf16x8;
typedef __attribute__((ext_vector_type(4))) float f32x4;
typedef __attribute__((ext_vector_type(4))) unsigned short u16x4;
typedef __attribute__((ext_vector_type(8))) unsigned short u16x8;

#define QSCALE (0.17677669529663687f * 1.4426950408889634f)  // log2e/sqrt(32)

static __device__ __forceinline__ unsigned short f2bf_rne(float f) {
    union { float f; unsigned int u; } v; v.f = f;
    unsigned int r = v.u + 0x7FFFu + ((v.u >> 16) & 1u);
    return (unsigned short)(r >> 16);
}

// ======================= Fragment-major layouts ==========================
// Weights wf: 32 n-tiles (q:0-7, k:8-15, v:16-23, o:24-31) x 4 kk x 64 lanes
//   x 8 elems.  B-frag: B[k=kk*32+quad*8+j][n=nt*16+col], lane=quad*16+col.
// Q  qf_ws: [bh][qi(128)][lane][8]   A-frag: Q[qi*16+col][quad*8+j]
// K  kf_ws: [bh][kbi(64)][f(2)][lane][8]  f=0: even keys kb+2*col, f=1: odd.
// V  vf_ws: [bh][kbi(64)][f(2)][lane][8]  B-frag: V[kb+quad*8+j][d], f=0:
//   d=col, f=1: d=col+16.
// ctx ctx_f: [mt(512)][kk(4)][lane][8]  A-frag: ctx[mt*16+col][kk*32+quad*8+j]

// ---- k0: weights -> bf16 fragment-major
__global__ __launch_bounds__(256) void k0_prep(
    const float* __restrict__ Wq, const float* __restrict__ Wk,
    const float* __restrict__ Wv, const float* __restrict__ Wo,
    unsigned short* __restrict__ wf)
{
    int tid = blockIdx.x * 256 + threadIdx.x;   // 0..8191
    int nt = tid >> 8, kk = (tid >> 6) & 3, lane = tid & 63;
    int col = lane & 15, quad = lane >> 4;
    const float* W = (nt < 8) ? Wq : (nt < 16) ? Wk : (nt < 24) ? Wv : Wo;
    int n = (nt & 7) * 16 + col;
    u16x8 v;
    #pragma unroll
    for (int j = 0; j < 8; ++j)
        v[j] = f2bf_rne(W[(kk * 32 + quad * 8 + j) * 128 + n]);
    *(u16x8*)(wf + (size_t)tid * 8) = v;
}

// ---- k1: LayerNorm -> bf16 -> MFMA QKV. 512 blocks x 16 rows; each of the
// 4 waves covers 6 of the 24 n-tiles (2 blocks/CU, 8 waves/CU).
__global__ __launch_bounds__(256) void k1_ln_qkv(
    const float* __restrict__ x, const unsigned short* __restrict__ wf,
    const float* __restrict__ bq, const float* __restrict__ bk,
    const float* __restrict__ bv,
    const float* __restrict__ gamma, const float* __restrict__ beta,
    unsigned short* __restrict__ qf_ws, unsigned short* __restrict__ kf_ws,
    unsigned short* __restrict__ vf_ws)
{
    __shared__ __align__(16) unsigned short xsh[16][136];
    const int t = threadIdx.x, w = t >> 6, lane = t & 63;
    const int row0 = blockIdx.x * 16;
    const float g0 = gamma[lane], g1 = gamma[lane + 64];
    const float be0 = beta[lane], be1 = beta[lane + 64];
    #pragma unroll
    for (int i = 0; i < 4; ++i) {
        int r = w * 4 + i;
        const float* xr = x + (size_t)(row0 + r) * 128;
        float x0 = xr[lane], x1 = xr[lane + 64];
        float s = x0 + x1, s2 = x0 * x0 + x1 * x1;
        #pragma unroll
        for (int off = 32; off > 0; off >>= 1) {
            s += __shfl_xor(s, off);
            s2 += __shfl_xor(s2, off);
        }
        float mu  = s * (1.0f / 128.0f);
        float var = s2 * (1.0f / 128.0f) - mu * mu;
        float rs  = rsqrtf(var + 1e-6f);
        xsh[r][lane]      = f2bf_rne((x0 - mu) * rs * g0 + be0);
        xsh[r][lane + 64] = f2bf_rne((x1 - mu) * rs * g1 + be1);
    }
    __syncthreads();

    const int col = lane & 15, quad = lane >> 4;
    bf16x8 a[4];
    #pragma unroll
    for (int kk = 0; kk < 4; ++kk)
        a[kk] = *(const bf16x8*)&xsh[col][kk * 32 + quad * 8];

    const int row_g0 = row0 + quad * 4;
    const int b = row_g0 >> 11;
    const int s0 = row_g0 & (SEQ - 1);
    const int nt0 = w * 6;

    for (int nt = nt0; nt < nt0 + 6; ++nt) {
        int n = nt * 16 + col;
        const unsigned short* wrow = wf + (size_t)(nt * 4) * 512 + lane * 8;
        f32x4 c = {0.f, 0.f, 0.f, 0.f};
        #pragma unroll
        for (int kk = 0; kk < 4; ++kk) {
            bf16x8 bfr = *(const bf16x8*)(wrow + kk * 512);
            c = __builtin_amdgcn_mfma_f32_16x16x32_bf16(a[kk], bfr, c, 0, 0, 0);
        }
        int m = nt >> 3;                 // 0=q 1=k 2=v (wave-uniform)
        int nn = n & 127, h = nn >> 5, dh = nn & 31, bh = b * NH + h;
        if (m == 0) {
            float bias = bq[nn];
            #pragma unroll
            for (int r = 0; r < 4; ++r) {
                int s = s0 + r;
                size_t idx = ((size_t)(bh * 128 + (s >> 4)) * 64
                              + (dh >> 3) * 16 + (s & 15)) * 8 + (dh & 7);
                qf_ws[idx] = f2bf_rne((c[r] + bias) * QSCALE);
            }
        } else if (m == 1) {
            float bias = bk[nn];
            #pragma unroll
            for (int r = 0; r < 4; ++r) {
                int s = s0 + r;
                size_t idx = ((size_t)((bh * 64 + (s >> 5)) * 2 + (s & 1)) * 64
                              + (dh >> 3) * 16 + ((s & 31) >> 1)) * 8 + (dh & 7);
                kf_ws[idx] = f2bf_rne(c[r] + bias);
            }
        } else {
            float bias = bv[nn];
            u16x4 pv;
            #pragma unroll
            for (int r = 0; r < 4; ++r) pv[r] = f2bf_rne(c[r] + bias);
            size_t idx = ((size_t)((bh * 64 + (s0 >> 5)) * 2 + (dh >> 4)) * 64
                          + ((s0 & 31) >> 3) * 16 + (dh & 15)) * 8 + (s0 & 7);
            *(u16x4*)(vf_ws + idx) = pv;
        }
    }
}

// ---- k2: attention. grid (64,16) = 1024 blocks (4 blocks/CU, 16 waves/CU).
// Block = 32 queries x all 2048 keys; wave w owns 512-key quarter (16 iters).
__global__ __launch_bounds__(256) void k2_attn(
    const unsigned short* __restrict__ qf_ws,
    const unsigned short* __restrict__ kf_ws,
    const unsigned short* __restrict__ vf_ws,
    unsigned short* __restrict__ ctx_f)
{
    __shared__ __align__(16) unsigned int p_sh[4][32][36];
    __shared__ __align__(16) float comb[4][32][33];
    __shared__ float lsh[4][32];
    const int w = threadIdx.x >> 6, lane = threadIdx.x & 63;
    const int col = lane & 15, quad = lane >> 4;
    const int hf = w;                      // key quarter
    const int bh = blockIdx.y;
    const int qi = blockIdx.x * 2;         // two 16-row q tiles

    const unsigned short* qb = qf_ws + (size_t)(bh * 128 + qi) * 512;
    const unsigned short* kb = kf_ws + (size_t)bh * 65536;
    const unsigned short* vb = vf_ws + (size_t)bh * 65536;

    bf16x8 qf0 = *(const bf16x8*)(qb + lane * 8);
    bf16x8 qf1 = *(const bf16x8*)(qb + 512 + lane * 8);

    f32x4 c00 = {0.f,0.f,0.f,0.f}, c01 = {0.f,0.f,0.f,0.f};
    f32x4 c10 = {0.f,0.f,0.f,0.f}, c11 = {0.f,0.f,0.f,0.f};
    float l0[4] = {0.f,0.f,0.f,0.f}, l1[4] = {0.f,0.f,0.f,0.f};

    const int kbi0 = hf * 16;
    bf16x8 kf0 = *(const bf16x8*)(kb + (size_t)kbi0 * 1024 + lane * 8);
    bf16x8 kf1 = *(const bf16x8*)(kb + (size_t)kbi0 * 1024 + 512 + lane * 8);
    bf16x8 vf0 = *(const bf16x8*)(vb + (size_t)kbi0 * 1024 + lane * 8);
    bf16x8 vf1 = *(const bf16x8*)(vb + (size_t)kbi0 * 1024 + 512 + lane * 8);

    for (int it = 0; it < 16; ++it) {
        int nkbi = kbi0 + ((it + 1) & 15);
        bf16x8 nkf0 = *(const bf16x8*)(kb + (size_t)nkbi * 1024 + lane * 8);
        bf16x8 nkf1 = *(const bf16x8*)(kb + (size_t)nkbi * 1024 + 512 + lane * 8);
        bf16x8 nvf0 = *(const bf16x8*)(vb + (size_t)nkbi * 1024 + lane * 8);
        bf16x8 nvf1 = *(const bf16x8*)(vb + (size_t)nkbi * 1024 + 512 + lane * 8);

        f32x4 z = {0.f,0.f,0.f,0.f};
        f32x4 s00 = __builtin_amdgcn_mfma_f32_16x16x32_bf16(qf0, kf0, z, 0, 0, 0);
        f32x4 s01 = __builtin_amdgcn_mfma_f32_16x16x32_bf16(qf0, kf1, z, 0, 0, 0);
        f32x4 s10 = __builtin_amdgcn_mfma_f32_16x16x32_bf16(qf1, kf0, z, 0, 0, 0);
        f32x4 s11 = __builtin_amdgcn_mfma_f32_16x16x32_bf16(qf1, kf1, z, 0, 0, 0);
        #pragma unroll
        for (int r = 0; r < 4; ++r) {
            float p00 = __builtin_amdgcn_exp2f(s00[r]);
            float p01 = __builtin_amdgcn_exp2f(s01[r]);
            l0[r] += p00 + p01;
            p_sh[w][quad * 4 + r][col] =
                (__float_as_uint(p00) >> 16) | (__float_as_uint(p01) & 0xFFFF0000u);
            float p10 = __builtin_amdgcn_exp2f(s10[r]);
            float p11 = __builtin_amdgcn_exp2f(s11[r]);
            l1[r] += p10 + p11;
            p_sh[w][16 + quad * 4 + r][col] =
                (__float_as_uint(p10) >> 16) | (__float_as_uint(p11) & 0xFFFF0000u);
        }
        bf16x8 pf0 = *(const bf16x8*)&p_sh[w][col][quad * 4];
        bf16x8 pf1 = *(const bf16x8*)&p_sh[w][16 + col][quad * 4];
        c00 = __builtin_amdgcn_mfma_f32_16x16x32_bf16(pf0, vf0, c00, 0, 0, 0);
        c01 = __builtin_amdgcn_mfma_f32_16x16x32_bf16(pf0, vf1, c01, 0, 0, 0);
        c10 = __builtin_amdgcn_mfma_f32_16x16x32_bf16(pf1, vf0, c10, 0, 0, 0);
        c11 = __builtin_amdgcn_mfma_f32_16x16x32_bf16(pf1, vf1, c11, 0, 0, 0);
        kf0 = nkf0; kf1 = nkf1; vf0 = nvf0; vf1 = nvf1;
    }

    #pragma unroll
    for (int r = 0; r < 4; ++r) {
        #pragma unroll
        for (int off = 1; off < 16; off <<= 1) {
            l0[r] += __shfl_xor(l0[r], off);
            l1[r] += __shfl_xor(l1[r], off);
        }
    }
    #pragma unroll
    for (int r = 0; r < 4; ++r) {
        int rr = quad * 4 + r;
        comb[hf][rr][col]           = c00[r];
        comb[hf][rr][16 + col]      = c01[r];
        comb[hf][16 + rr][col]      = c10[r];
        comb[hf][16 + rr][16 + col] = c11[r];
    }
    if (col == 0) {
        #pragma unroll
        for (int r = 0; r < 4; ++r) {
            lsh[hf][quad * 4 + r]      = l0[r];
            lsh[hf][16 + quad * 4 + r] = l1[r];
        }
    }
    __syncthreads();
    {
        int row = threadIdx.x >> 3;        // 0..31
        int cg = threadIdx.x & 7;          // 4-col group within head
        int d0 = cg * 4;
        float linv = 1.0f / (lsh[0][row] + lsh[1][row] + lsh[2][row] + lsh[3][row]);
        u16x4 ov;
        #pragma unroll
        for (int j = 0; j < 4; ++j) {
            int cc = d0 + j;
            ov[j] = f2bf_rne((comb[0][row][cc] + comb[1][row][cc]
                            + comb[2][row][cc] + comb[3][row][cc]) * linv);
        }
        int s_loc = blockIdx.x * 32 + row;
        int b = bh >> 2, h = bh & 3;
        int s_g = b * SEQ + s_loc;
        size_t idx = (((size_t)(s_g >> 4) * 4 + h) * 64
                      + (d0 >> 3) * 16 + (s_g & 15)) * 8 + (d0 & 7);
        *(u16x4*)(ctx_f + idx) = ov;
    }
}

// ---- k3: out = ctx @ Wo + bo + x. 512 blocks x 16 rows; wave w covers 2
// of the 8 n-tiles.
__global__ __launch_bounds__(256) void k3_out(
    const unsigned short* __restrict__ ctx_f,
    const unsigned short* __restrict__ wf, const float* __restrict__ bo,
    const float* __restrict__ x, float* __restrict__ out)
{
    const int t = threadIdx.x, w = t >> 6, lane = t & 63;
    const int col = lane & 15, quad = lane >> 4;
    const int mt = blockIdx.x;
    bf16x8 a[4];
    #pragma unroll
    for (int kk = 0; kk < 4; ++kk)
        a[kk] = *(const bf16x8*)(ctx_f + ((size_t)(mt * 4 + kk) * 64 + lane) * 8);
    #pragma unroll
    for (int i = 0; i < 2; ++i) {
        int ntl = w * 2 + i;                 // 0..7 within Wo
        int nt_g = 24 + ntl;
        int n = ntl * 16 + col;
        f32x4 c = {0.f, 0.f, 0.f, 0.f};
        #pragma unroll
        for (int kk = 0; kk < 4; ++kk) {
            bf16x8 bfr = *(const bf16x8*)(wf + ((size_t)(nt_g * 4 + kk) * 64 + lane) * 8);
            c = __builtin_amdgcn_mfma_f32_16x16x32_bf16(a[kk], bfr, c, 0, 0, 0);
        }
        float bias = bo[n];
        #pragma unroll
        for (int r = 0; r < 4; ++r) {
            size_t row_g = (size_t)mt * 16 + quad * 4 + r;
            out[row_g * 128 + n] = c[r] + bias + x[row_g * 128 + n];
        }
    }
}

extern "C" void kernel_launch(void* const* d_in, const int* in_sizes, int n_in,
                              void* d_out, int out_size, void* d_ws, size_t ws_size,
                              hipStream_t stream) {
    const float* x     = (const float*)d_in[0];
    const float* Wq    = (const float*)d_in[1];
    const float* bq    = (const float*)d_in[2];
    const float* Wk    = (const float*)d_in[3];
    const float* bk    = (const float*)d_in[4];
    const float* Wv    = (const float*)d_in[5];
    const float* bv    = (const float*)d_in[6];
    const float* gamma = (const float*)d_in[7];
    const float* beta  = (const float*)d_in[8];
    const float* Wo    = (const float*)d_in[9];
    const float* bo    = (const float*)d_in[10];
    float* out = (float*)d_out;

    const size_t QKV_ELEMS = (size_t)BHN * SEQ * DH;  // 1M
    unsigned short* qf_ws = (unsigned short*)d_ws;
    unsigned short* kf_ws = qf_ws + QKV_ELEMS;
    unsigned short* vf_ws = kf_ws + QKV_ELEMS;
    unsigned short* ctx_f = vf_ws + QKV_ELEMS;
    unsigned short* wf    = ctx_f + QKV_ELEMS;        // 512*128 bf16 frag-major

    k0_prep<<<32, 256, 0, stream>>>(Wq, Wk, Wv, Wo, wf);
    k1_ln_qkv<<<512, 256, 0, stream>>>(x, wf, bq, bk, bv, gamma, beta,
                                       qf_ws, kf_ws, vf_ws);
    k2_attn<<<dim3(SEQ / 32, BHN), 256, 0, stream>>>(qf_ws, kf_ws, vf_ws, ctx_f);
    k3_out<<<512, 256, 0, stream>>>(ctx_f, wf, bo, x, out);
}

// Round 6
// 103.598 us; speedup vs baseline: 1.7266x; 1.0492x over previous
//
#include <hip/hip_runtime.h>

#define D_MODEL 128
#define SEQ 2048
#define NH 4
#define DH 32
#define NBATCH 4
#define BHN 16

typedef __attribute__((ext_vector_type(8))) short bf16x8;
typedef __attribute__((ext_vector_type(4))) float f32x4;
typedef __attribute__((ext_vector_type(4))) unsigned short u16x4;
typedef __attribute__((ext_vector_type(8))) unsigned short u16x8;

#define QSCALE (0.17677669529663687f * 1.4426950408889634f)  // log2e/sqrt(32)

static __device__ __forceinline__ unsigned short f2bf_rne(float f) {
    union { float f; unsigned int u; } v; v.f = f;
    unsigned int r = v.u + 0x7FFFu + ((v.u >> 16) & 1u);
    return (unsigned short)(r >> 16);
}

// ======================= Fragment-major layouts ==========================
// Weights wf: 32 n-tiles (q:0-7, k:8-15, v:16-23, o:24-31) x 4 kk x 64 lanes
//   x 8 elems.  B-frag: B[k=kk*32+quad*8+j][n=nt*16+col], lane=quad*16+col.
// Q  qf_ws: [bh][qi(128)][lane][8]   A-frag: Q[qi*16+col][quad*8+j]
// K  kf_ws: [bh][kbi(64)][f(2)][lane][8]  f=0: even keys kb+2*col, f=1: odd.
// V  vf_ws: [bh][kbi(64)][f(2)][lane][8]  B-frag: V[kb+quad*8+j][d], f=0:
//   d=col, f=1: d=col+16.

// ---- k0: weights -> bf16 fragment-major
__global__ __launch_bounds__(256) void k0_prep(
    const float* __restrict__ Wq, const float* __restrict__ Wk,
    const float* __restrict__ Wv, const float* __restrict__ Wo,
    unsigned short* __restrict__ wf)
{
    int tid = blockIdx.x * 256 + threadIdx.x;   // 0..8191
    int nt = tid >> 8, kk = (tid >> 6) & 3, lane = tid & 63;
    int col = lane & 15, quad = lane >> 4;
    const float* W = (nt < 8) ? Wq : (nt < 16) ? Wk : (nt < 24) ? Wv : Wo;
    int n = (nt & 7) * 16 + col;
    u16x8 v;
    #pragma unroll
    for (int j = 0; j < 8; ++j)
        v[j] = f2bf_rne(W[(kk * 32 + quad * 8 + j) * 128 + n]);
    *(u16x8*)(wf + (size_t)tid * 8) = v;
}

// ---- k1: LayerNorm -> bf16 -> MFMA QKV. 512 blocks x 16 rows; wave covers
// 6 of the 24 n-tiles.
__global__ __launch_bounds__(256) void k1_ln_qkv(
    const float* __restrict__ x, const unsigned short* __restrict__ wf,
    const float* __restrict__ bq, const float* __restrict__ bk,
    const float* __restrict__ bv,
    const float* __restrict__ gamma, const float* __restrict__ beta,
    unsigned short* __restrict__ qf_ws, unsigned short* __restrict__ kf_ws,
    unsigned short* __restrict__ vf_ws)
{
    __shared__ __align__(16) unsigned short xsh[16][136];
    const int t = threadIdx.x, w = t >> 6, lane = t & 63;
    const int row0 = blockIdx.x * 16;
    const float g0 = gamma[lane], g1 = gamma[lane + 64];
    const float be0 = beta[lane], be1 = beta[lane + 64];
    #pragma unroll
    for (int i = 0; i < 4; ++i) {
        int r = w * 4 + i;
        const float* xr = x + (size_t)(row0 + r) * 128;
        float x0 = xr[lane], x1 = xr[lane + 64];
        float s = x0 + x1, s2 = x0 * x0 + x1 * x1;
        #pragma unroll
        for (int off = 32; off > 0; off >>= 1) {
            s += __shfl_xor(s, off);
            s2 += __shfl_xor(s2, off);
        }
        float mu  = s * (1.0f / 128.0f);
        float var = s2 * (1.0f / 128.0f) - mu * mu;
        float rs  = rsqrtf(var + 1e-6f);
        xsh[r][lane]      = f2bf_rne((x0 - mu) * rs * g0 + be0);
        xsh[r][lane + 64] = f2bf_rne((x1 - mu) * rs * g1 + be1);
    }
    __syncthreads();

    const int col = lane & 15, quad = lane >> 4;
    bf16x8 a[4];
    #pragma unroll
    for (int kk = 0; kk < 4; ++kk)
        a[kk] = *(const bf16x8*)&xsh[col][kk * 32 + quad * 8];

    const int row_g0 = row0 + quad * 4;
    const int b = row_g0 >> 11;
    const int s0 = row_g0 & (SEQ - 1);
    const int nt0 = w * 6;

    for (int nt = nt0; nt < nt0 + 6; ++nt) {
        int n = nt * 16 + col;
        const unsigned short* wrow = wf + (size_t)(nt * 4) * 512 + lane * 8;
        f32x4 c = {0.f, 0.f, 0.f, 0.f};
        #pragma unroll
        for (int kk = 0; kk < 4; ++kk) {
            bf16x8 bfr = *(const bf16x8*)(wrow + kk * 512);
            c = __builtin_amdgcn_mfma_f32_16x16x32_bf16(a[kk], bfr, c, 0, 0, 0);
        }
        int m = nt >> 3;                 // 0=q 1=k 2=v (wave-uniform)
        int nn = n & 127, h = nn >> 5, dh = nn & 31, bh = b * NH + h;
        if (m == 0) {
            float bias = bq[nn];
            #pragma unroll
            for (int r = 0; r < 4; ++r) {
                int s = s0 + r;
                size_t idx = ((size_t)(bh * 128 + (s >> 4)) * 64
                              + (dh >> 3) * 16 + (s & 15)) * 8 + (dh & 7);
                qf_ws[idx] = f2bf_rne((c[r] + bias) * QSCALE);
            }
        } else if (m == 1) {
            float bias = bk[nn];
            #pragma unroll
            for (int r = 0; r < 4; ++r) {
                int s = s0 + r;
                size_t idx = ((size_t)((bh * 64 + (s >> 5)) * 2 + (s & 1)) * 64
                              + (dh >> 3) * 16 + ((s & 31) >> 1)) * 8 + (dh & 7);
                kf_ws[idx] = f2bf_rne(c[r] + bias);
            }
        } else {
            float bias = bv[nn];
            u16x4 pv;
            #pragma unroll
            for (int r = 0; r < 4; ++r) pv[r] = f2bf_rne(c[r] + bias);
            size_t idx = ((size_t)((bh * 64 + (s0 >> 5)) * 2 + (dh >> 4)) * 64
                          + ((s0 & 31) >> 3) * 16 + (dh & 15)) * 8 + (s0 & 7);
            *(u16x4*)(vf_ws + idx) = pv;
        }
    }
}

// ---- k23: attention + out-projection + residual, fused.
// grid (64, 4) = 256 blocks x 512 threads (8 waves). Block = 32 queries of
// batch b, ALL 4 heads. Wave w = (head = w>>1, key-half = w&1, 32 iters).
// After key loop: per-head halves combine linearly in LDS, normalize ->
// bf16 ctx_sh, then each wave computes one 16-col tile of ctx @ Wo + bo + x
// for BOTH 16-row m-tiles (R5 bug: only did mt=0, rows 16-31 never written).
__global__ __launch_bounds__(512) void k23_attn_out(
    const unsigned short* __restrict__ qf_ws,
    const unsigned short* __restrict__ kf_ws,
    const unsigned short* __restrict__ vf_ws,
    const unsigned short* __restrict__ wf,
    const float* __restrict__ bo, const float* __restrict__ x,
    float* __restrict__ out)
{
    __shared__ __align__(16) unsigned int p_sh[8][32][36];
    __shared__ __align__(16) float comb[8][32][33];
    __shared__ float lsh[8][32];
    __shared__ __align__(16) unsigned short ctx_sh[32][136];

    const int w = threadIdx.x >> 6, lane = threadIdx.x & 63;
    const int col = lane & 15, quad = lane >> 4;
    const int h = w >> 1, kh = w & 1;
    const int b = blockIdx.y;
    const int bh = b * NH + h;
    const int q0 = blockIdx.x * 32;              // block's first q row
    const int qi = blockIdx.x * 2;               // 16-row q tile index

    const unsigned short* qb = qf_ws + (size_t)(bh * 128 + qi) * 512;
    const unsigned short* kb0 = kf_ws + (size_t)bh * 65536 + (size_t)(kh * 32) * 1024;
    const unsigned short* vb0 = vf_ws + (size_t)bh * 65536 + (size_t)(kh * 32) * 1024;

    bf16x8 qf0 = *(const bf16x8*)(qb + lane * 8);
    bf16x8 qf1 = *(const bf16x8*)(qb + 512 + lane * 8);

    f32x4 c00 = {0.f,0.f,0.f,0.f}, c01 = {0.f,0.f,0.f,0.f};
    f32x4 c10 = {0.f,0.f,0.f,0.f}, c11 = {0.f,0.f,0.f,0.f};
    float l0[4] = {0.f,0.f,0.f,0.f}, l1[4] = {0.f,0.f,0.f,0.f};

    const unsigned short* pk = kb0;
    const unsigned short* pv = vb0;
    bf16x8 kf0 = *(const bf16x8*)(pk + lane * 8);
    bf16x8 kf1 = *(const bf16x8*)(pk + 512 + lane * 8);
    bf16x8 vf0 = *(const bf16x8*)(pv + lane * 8);
    bf16x8 vf1 = *(const bf16x8*)(pv + 512 + lane * 8);

    for (int it = 0; it < 32; ++it) {
        const unsigned short* nk = (it == 31) ? kb0 : pk + 1024;
        const unsigned short* nv = (it == 31) ? vb0 : pv + 1024;
        bf16x8 nkf0 = *(const bf16x8*)(nk + lane * 8);
        bf16x8 nkf1 = *(const bf16x8*)(nk + 512 + lane * 8);
        bf16x8 nvf0 = *(const bf16x8*)(nv + lane * 8);
        bf16x8 nvf1 = *(const bf16x8*)(nv + 512 + lane * 8);

        f32x4 z = {0.f,0.f,0.f,0.f};
        f32x4 s00 = __builtin_amdgcn_mfma_f32_16x16x32_bf16(qf0, kf0, z, 0, 0, 0);
        f32x4 s01 = __builtin_amdgcn_mfma_f32_16x16x32_bf16(qf0, kf1, z, 0, 0, 0);
        f32x4 s10 = __builtin_amdgcn_mfma_f32_16x16x32_bf16(qf1, kf0, z, 0, 0, 0);
        f32x4 s11 = __builtin_amdgcn_mfma_f32_16x16x32_bf16(qf1, kf1, z, 0, 0, 0);
        #pragma unroll
        for (int r = 0; r < 4; ++r) {
            float p00 = __builtin_amdgcn_exp2f(s00[r]);
            float p01 = __builtin_amdgcn_exp2f(s01[r]);
            l0[r] += p00 + p01;
            p_sh[w][quad * 4 + r][col] =
                (__float_as_uint(p00) >> 16) | (__float_as_uint(p01) & 0xFFFF0000u);
            float p10 = __builtin_amdgcn_exp2f(s10[r]);
            float p11 = __builtin_amdgcn_exp2f(s11[r]);
            l1[r] += p10 + p11;
            p_sh[w][16 + quad * 4 + r][col] =
                (__float_as_uint(p10) >> 16) | (__float_as_uint(p11) & 0xFFFF0000u);
        }
        bf16x8 pf0 = *(const bf16x8*)&p_sh[w][col][quad * 4];
        bf16x8 pf1 = *(const bf16x8*)&p_sh[w][16 + col][quad * 4];
        c00 = __builtin_amdgcn_mfma_f32_16x16x32_bf16(pf0, vf0, c00, 0, 0, 0);
        c01 = __builtin_amdgcn_mfma_f32_16x16x32_bf16(pf0, vf1, c01, 0, 0, 0);
        c10 = __builtin_amdgcn_mfma_f32_16x16x32_bf16(pf1, vf0, c10, 0, 0, 0);
        c11 = __builtin_amdgcn_mfma_f32_16x16x32_bf16(pf1, vf1, c11, 0, 0, 0);
        kf0 = nkf0; kf1 = nkf1; vf0 = nvf0; vf1 = nvf1;
        pk = nk; pv = nv;
    }

    #pragma unroll
    for (int r = 0; r < 4; ++r) {
        #pragma unroll
        for (int off = 1; off < 16; off <<= 1) {
            l0[r] += __shfl_xor(l0[r], off);
            l1[r] += __shfl_xor(l1[r], off);
        }
    }
    #pragma unroll
    for (int r = 0; r < 4; ++r) {
        int rr = quad * 4 + r;
        comb[w][rr][col]           = c00[r];
        comb[w][rr][16 + col]      = c01[r];
        comb[w][16 + rr][col]      = c10[r];
        comb[w][16 + rr][16 + col] = c11[r];
    }
    if (col == 0) {
        #pragma unroll
        for (int r = 0; r < 4; ++r) {
            lsh[w][quad * 4 + r]      = l0[r];
            lsh[w][16 + quad * 4 + r] = l1[r];
        }
    }
    __syncthreads();

    // combine key-halves, normalize, store bf16 ctx_sh[32 rows][128 d]
    {
        int row = threadIdx.x >> 4;          // 0..31
        int dg  = (threadIdx.x & 15) * 8;    // 8-col group
        int hh  = dg >> 5;                   // head of this col group
        float linv = 1.0f / (lsh[2 * hh][row] + lsh[2 * hh + 1][row]);
        int dl = dg & 31;
        u16x8 ov;
        #pragma unroll
        for (int j = 0; j < 8; ++j)
            ov[j] = f2bf_rne((comb[2 * hh][row][dl + j]
                            + comb[2 * hh + 1][row][dl + j]) * linv);
        *(u16x8*)&ctx_sh[row][dg] = ov;
    }
    __syncthreads();

    // out-projection: wave w handles n-tile w, BOTH 16-row m-tiles
    #pragma unroll
    for (int mt = 0; mt < 2; ++mt) {
        bf16x8 a[4];
        #pragma unroll
        for (int kk = 0; kk < 4; ++kk)
            a[kk] = *(const bf16x8*)&ctx_sh[mt * 16 + col][kk * 32 + quad * 8];
        int n = w * 16 + col;
        int nt_g = 24 + w;
        f32x4 c = {0.f, 0.f, 0.f, 0.f};
        #pragma unroll
        for (int kk = 0; kk < 4; ++kk) {
            bf16x8 bfr = *(const bf16x8*)(wf + ((size_t)(nt_g * 4 + kk) * 64 + lane) * 8);
            c = __builtin_amdgcn_mfma_f32_16x16x32_bf16(a[kk], bfr, c, 0, 0, 0);
        }
        float bias = bo[n];
        #pragma unroll
        for (int r = 0; r < 4; ++r) {
            size_t row_g = (size_t)b * SEQ + q0 + mt * 16 + quad * 4 + r;
            out[row_g * 128 + n] = c[r] + bias + x[row_g * 128 + n];
        }
    }
}

extern "C" void kernel_launch(void* const* d_in, const int* in_sizes, int n_in,
                              void* d_out, int out_size, void* d_ws, size_t ws_size,
                              hipStream_t stream) {
    const float* x     = (const float*)d_in[0];
    const float* Wq    = (const float*)d_in[1];
    const float* bq    = (const float*)d_in[2];
    const float* Wk    = (const float*)d_in[3];
    const float* bk    = (const float*)d_in[4];
    const float* Wv    = (const float*)d_in[5];
    const float* bv    = (const float*)d_in[6];
    const float* gamma = (const float*)d_in[7];
    const float* beta  = (const float*)d_in[8];
    const float* Wo    = (const float*)d_in[9];
    const float* bo    = (const float*)d_in[10];
    float* out = (float*)d_out;

    const size_t QKV_ELEMS = (size_t)BHN * SEQ * DH;  // 1M
    unsigned short* qf_ws = (unsigned short*)d_ws;
    unsigned short* kf_ws = qf_ws + QKV_ELEMS;
    unsigned short* vf_ws = kf_ws + QKV_ELEMS;
    unsigned short* wf    = vf_ws + QKV_ELEMS;        // 512*128 bf16 frag-major

    k0_prep<<<32, 256, 0, stream>>>(Wq, Wk, Wv, Wo, wf);
    k1_ln_qkv<<<512, 256, 0, stream>>>(x, wf, bq, bk, bv, gamma, beta,
                                       qf_ws, kf_ws, vf_ws);
    k23_attn_out<<<dim3(64, 4), 512, 0, stream>>>(qf_ws, kf_ws, vf_ws, wf,
                                                  bo, x, out);
}

// Round 7
// 102.877 us; speedup vs baseline: 1.7387x; 1.0070x over previous
//
#include <hip/hip_runtime.h>

#define D_MODEL 128
#define SEQ 2048
#define NH 4
#define DH 32
#define NBATCH 4
#define BHN 16

typedef __attribute__((ext_vector_type(8))) short bf16x8;
typedef __attribute__((ext_vector_type(4))) float f32x4;
typedef __attribute__((ext_vector_type(4))) unsigned short u16x4;
typedef __attribute__((ext_vector_type(8))) unsigned short u16x8;

#define QSCALE (0.17677669529663687f * 1.4426950408889634f)  // log2e/sqrt(32)

static __device__ __forceinline__ unsigned short f2bf_rne(float f) {
    union { float f; unsigned int u; } v; v.f = f;
    unsigned int r = v.u + 0x7FFFu + ((v.u >> 16) & 1u);
    return (unsigned short)(r >> 16);
}

// ======================= Fragment-major layouts ==========================
// Weights wf: 32 n-tiles (q:0-7, k:8-15, v:16-23, o:24-31) x 4 kk x 64 lanes
//   x 8 elems.  B-frag: B[k=kk*32+quad*8+j][n=nt*16+col], lane=quad*16+col.
// Q  qf_ws: [bh][qi(128)][lane][8]   A-frag: Q[qi*16+col][quad*8+j]
// K  kf_ws: [bh][kbi(64)][f(2)][lane][8]  f=0: even keys kb+2*col, f=1: odd.
// V  vf_ws: [bh][kbi(64)][f(2)][lane][8]  B-frag: V[kb+quad*8+j][d], f=0:
//   d=col, f=1: d=col+16.

// ---- k0: weights -> bf16 fragment-major
__global__ __launch_bounds__(256) void k0_prep(
    const float* __restrict__ Wq, const float* __restrict__ Wk,
    const float* __restrict__ Wv, const float* __restrict__ Wo,
    unsigned short* __restrict__ wf)
{
    int tid = blockIdx.x * 256 + threadIdx.x;   // 0..8191
    int nt = tid >> 8, kk = (tid >> 6) & 3, lane = tid & 63;
    int col = lane & 15, quad = lane >> 4;
    const float* W = (nt < 8) ? Wq : (nt < 16) ? Wk : (nt < 24) ? Wv : Wo;
    int n = (nt & 7) * 16 + col;
    u16x8 v;
    #pragma unroll
    for (int j = 0; j < 8; ++j)
        v[j] = f2bf_rne(W[(kk * 32 + quad * 8 + j) * 128 + n]);
    *(u16x8*)(wf + (size_t)tid * 8) = v;
}

// ---- k1: LayerNorm -> bf16 -> MFMA QKV. 512 blocks x 16 rows; wave covers
// 6 of the 24 n-tiles.
__global__ __launch_bounds__(256) void k1_ln_qkv(
    const float* __restrict__ x, const unsigned short* __restrict__ wf,
    const float* __restrict__ bq, const float* __restrict__ bk,
    const float* __restrict__ bv,
    const float* __restrict__ gamma, const float* __restrict__ beta,
    unsigned short* __restrict__ qf_ws, unsigned short* __restrict__ kf_ws,
    unsigned short* __restrict__ vf_ws)
{
    __shared__ __align__(16) unsigned short xsh[16][136];
    const int t = threadIdx.x, w = t >> 6, lane = t & 63;
    const int row0 = blockIdx.x * 16;
    const float g0 = gamma[lane], g1 = gamma[lane + 64];
    const float be0 = beta[lane], be1 = beta[lane + 64];
    #pragma unroll
    for (int i = 0; i < 4; ++i) {
        int r = w * 4 + i;
        const float* xr = x + (size_t)(row0 + r) * 128;
        float x0 = xr[lane], x1 = xr[lane + 64];
        float s = x0 + x1, s2 = x0 * x0 + x1 * x1;
        #pragma unroll
        for (int off = 32; off > 0; off >>= 1) {
            s += __shfl_xor(s, off);
            s2 += __shfl_xor(s2, off);
        }
        float mu  = s * (1.0f / 128.0f);
        float var = s2 * (1.0f / 128.0f) - mu * mu;
        float rs  = rsqrtf(var + 1e-6f);
        xsh[r][lane]      = f2bf_rne((x0 - mu) * rs * g0 + be0);
        xsh[r][lane + 64] = f2bf_rne((x1 - mu) * rs * g1 + be1);
    }
    __syncthreads();

    const int col = lane & 15, quad = lane >> 4;
    bf16x8 a[4];
    #pragma unroll
    for (int kk = 0; kk < 4; ++kk)
        a[kk] = *(const bf16x8*)&xsh[col][kk * 32 + quad * 8];

    const int row_g0 = row0 + quad * 4;
    const int b = row_g0 >> 11;
    const int s0 = row_g0 & (SEQ - 1);
    const int nt0 = w * 6;

    for (int nt = nt0; nt < nt0 + 6; ++nt) {
        int n = nt * 16 + col;
        const unsigned short* wrow = wf + (size_t)(nt * 4) * 512 + lane * 8;
        f32x4 c = {0.f, 0.f, 0.f, 0.f};
        #pragma unroll
        for (int kk = 0; kk < 4; ++kk) {
            bf16x8 bfr = *(const bf16x8*)(wrow + kk * 512);
            c = __builtin_amdgcn_mfma_f32_16x16x32_bf16(a[kk], bfr, c, 0, 0, 0);
        }
        int m = nt >> 3;                 // 0=q 1=k 2=v (wave-uniform)
        int nn = n & 127, h = nn >> 5, dh = nn & 31, bh = b * NH + h;
        if (m == 0) {
            float bias = bq[nn];
            #pragma unroll
            for (int r = 0; r < 4; ++r) {
                int s = s0 + r;
                size_t idx = ((size_t)(bh * 128 + (s >> 4)) * 64
                              + (dh >> 3) * 16 + (s & 15)) * 8 + (dh & 7);
                qf_ws[idx] = f2bf_rne((c[r] + bias) * QSCALE);
            }
        } else if (m == 1) {
            float bias = bk[nn];
            #pragma unroll
            for (int r = 0; r < 4; ++r) {
                int s = s0 + r;
                size_t idx = ((size_t)((bh * 64 + (s >> 5)) * 2 + (s & 1)) * 64
                              + (dh >> 3) * 16 + ((s & 31) >> 1)) * 8 + (dh & 7);
                kf_ws[idx] = f2bf_rne(c[r] + bias);
            }
        } else {
            float bias = bv[nn];
            u16x4 pv;
            #pragma unroll
            for (int r = 0; r < 4; ++r) pv[r] = f2bf_rne(c[r] + bias);
            size_t idx = ((size_t)((bh * 64 + (s0 >> 5)) * 2 + (dh >> 4)) * 64
                          + ((s0 & 31) >> 3) * 16 + (dh & 15)) * 8 + (s0 & 7);
            *(u16x4*)(vf_ws + idx) = pv;
        }
    }
}

// ---- k23: attention + out-projection + residual, fused. 16 waves.
// grid (64, 4) = 256 blocks x 1024 threads. Block = 32 queries of batch b,
// ALL 4 heads. Wave w = (head = w>>2, key-quarter kh = w&3), 16 iters.
// 4 waves/SIMD in the main loop (vs 2 in R6) to hide the per-iter
// MFMA->exp2->LDS-roundtrip->MFMA chain (~300 cyc).
__global__ __launch_bounds__(1024) void k23_attn_out(
    const unsigned short* __restrict__ qf_ws,
    const unsigned short* __restrict__ kf_ws,
    const unsigned short* __restrict__ vf_ws,
    const unsigned short* __restrict__ wf,
    const float* __restrict__ bo, const float* __restrict__ x,
    float* __restrict__ out)
{
    __shared__ __align__(16) unsigned int p_sh[16][32][36];   // 73.7 KB
    __shared__ __align__(16) float comb[16][32][33];          // 67.6 KB
    __shared__ float lsh[16][32];                             // 2 KB
    __shared__ __align__(16) unsigned short ctx_sh[32][136];  // 8.7 KB

    const int w = threadIdx.x >> 6, lane = threadIdx.x & 63;
    const int col = lane & 15, quad = lane >> 4;
    const int h = w >> 2, kh = w & 3;
    const int b = blockIdx.y;
    const int bh = b * NH + h;
    const int q0 = blockIdx.x * 32;              // block's first q row
    const int qi = blockIdx.x * 2;               // 16-row q tile index

    const unsigned short* qb = qf_ws + (size_t)(bh * 128 + qi) * 512;
    const unsigned short* kb0 = kf_ws + (size_t)bh * 65536 + (size_t)(kh * 16) * 1024;
    const unsigned short* vb0 = vf_ws + (size_t)bh * 65536 + (size_t)(kh * 16) * 1024;

    bf16x8 qf0 = *(const bf16x8*)(qb + lane * 8);
    bf16x8 qf1 = *(const bf16x8*)(qb + 512 + lane * 8);

    f32x4 c00 = {0.f,0.f,0.f,0.f}, c01 = {0.f,0.f,0.f,0.f};
    f32x4 c10 = {0.f,0.f,0.f,0.f}, c11 = {0.f,0.f,0.f,0.f};
    float l0[4] = {0.f,0.f,0.f,0.f}, l1[4] = {0.f,0.f,0.f,0.f};

    const unsigned short* pk = kb0;
    const unsigned short* pv = vb0;
    bf16x8 kf0 = *(const bf16x8*)(pk + lane * 8);
    bf16x8 kf1 = *(const bf16x8*)(pk + 512 + lane * 8);
    bf16x8 vf0 = *(const bf16x8*)(pv + lane * 8);
    bf16x8 vf1 = *(const bf16x8*)(pv + 512 + lane * 8);

    for (int it = 0; it < 16; ++it) {
        const unsigned short* nk = (it == 15) ? kb0 : pk + 1024;
        const unsigned short* nv = (it == 15) ? vb0 : pv + 1024;
        bf16x8 nkf0 = *(const bf16x8*)(nk + lane * 8);
        bf16x8 nkf1 = *(const bf16x8*)(nk + 512 + lane * 8);
        bf16x8 nvf0 = *(const bf16x8*)(nv + lane * 8);
        bf16x8 nvf1 = *(const bf16x8*)(nv + 512 + lane * 8);

        f32x4 z = {0.f,0.f,0.f,0.f};
        f32x4 s00 = __builtin_amdgcn_mfma_f32_16x16x32_bf16(qf0, kf0, z, 0, 0, 0);
        f32x4 s01 = __builtin_amdgcn_mfma_f32_16x16x32_bf16(qf0, kf1, z, 0, 0, 0);
        f32x4 s10 = __builtin_amdgcn_mfma_f32_16x16x32_bf16(qf1, kf0, z, 0, 0, 0);
        f32x4 s11 = __builtin_amdgcn_mfma_f32_16x16x32_bf16(qf1, kf1, z, 0, 0, 0);
        #pragma unroll
        for (int r = 0; r < 4; ++r) {
            float p00 = __builtin_amdgcn_exp2f(s00[r]);
            float p01 = __builtin_amdgcn_exp2f(s01[r]);
            l0[r] += p00 + p01;
            p_sh[w][quad * 4 + r][col] =
                (__float_as_uint(p00) >> 16) | (__float_as_uint(p01) & 0xFFFF0000u);
            float p10 = __builtin_amdgcn_exp2f(s10[r]);
            float p11 = __builtin_amdgcn_exp2f(s11[r]);
            l1[r] += p10 + p11;
            p_sh[w][16 + quad * 4 + r][col] =
                (__float_as_uint(p10) >> 16) | (__float_as_uint(p11) & 0xFFFF0000u);
        }
        bf16x8 pf0 = *(const bf16x8*)&p_sh[w][col][quad * 4];
        bf16x8 pf1 = *(const bf16x8*)&p_sh[w][16 + col][quad * 4];
        c00 = __builtin_amdgcn_mfma_f32_16x16x32_bf16(pf0, vf0, c00, 0, 0, 0);
        c01 = __builtin_amdgcn_mfma_f32_16x16x32_bf16(pf0, vf1, c01, 0, 0, 0);
        c10 = __builtin_amdgcn_mfma_f32_16x16x32_bf16(pf1, vf0, c10, 0, 0, 0);
        c11 = __builtin_amdgcn_mfma_f32_16x16x32_bf16(pf1, vf1, c11, 0, 0, 0);
        kf0 = nkf0; kf1 = nkf1; vf0 = nvf0; vf1 = nvf1;
        pk = nk; pv = nv;
    }

    #pragma unroll
    for (int r = 0; r < 4; ++r) {
        #pragma unroll
        for (int off = 1; off < 16; off <<= 1) {
            l0[r] += __shfl_xor(l0[r], off);
            l1[r] += __shfl_xor(l1[r], off);
        }
    }
    #pragma unroll
    for (int r = 0; r < 4; ++r) {
        int rr = quad * 4 + r;
        comb[w][rr][col]           = c00[r];
        comb[w][rr][16 + col]      = c01[r];
        comb[w][16 + rr][col]      = c10[r];
        comb[w][16 + rr][16 + col] = c11[r];
    }
    if (col == 0) {
        #pragma unroll
        for (int r = 0; r < 4; ++r) {
            lsh[w][quad * 4 + r]      = l0[r];
            lsh[w][16 + quad * 4 + r] = l1[r];
        }
    }
    __syncthreads();

    // combine 4 key-quarters, normalize, store bf16 ctx_sh[32 rows][128 d]
    {
        int row = threadIdx.x >> 5;          // 0..31
        int dg  = (threadIdx.x & 31) * 4;    // 4-col group
        int hh  = dg >> 5;                   // head of this col group
        int wb  = hh * 4;
        float linv = 1.0f / (lsh[wb][row] + lsh[wb + 1][row]
                           + lsh[wb + 2][row] + lsh[wb + 3][row]);
        int dl = dg & 31;
        u16x4 ov;
        #pragma unroll
        for (int j = 0; j < 4; ++j)
            ov[j] = f2bf_rne((comb[wb][row][dl + j] + comb[wb + 1][row][dl + j]
                            + comb[wb + 2][row][dl + j] + comb[wb + 3][row][dl + j])
                             * linv);
        *(u16x4*)&ctx_sh[row][dg] = ov;
    }
    __syncthreads();

    // out-projection: 16 waves <-> 16 (n-tile, m-tile) units
    {
        int nt = w & 7, mt = w >> 3;
        bf16x8 a[4];
        #pragma unroll
        for (int kk = 0; kk < 4; ++kk)
            a[kk] = *(const bf16x8*)&ctx_sh[mt * 16 + col][kk * 32 + quad * 8];
        int n = nt * 16 + col;
        int nt_g = 24 + nt;
        f32x4 c = {0.f, 0.f, 0.f, 0.f};
        #pragma unroll
        for (int kk = 0; kk < 4; ++kk) {
            bf16x8 bfr = *(const bf16x8*)(wf + ((size_t)(nt_g * 4 + kk) * 64 + lane) * 8);
            c = __builtin_amdgcn_mfma_f32_16x16x32_bf16(a[kk], bfr, c, 0, 0, 0);
        }
        float bias = bo[n];
        #pragma unroll
        for (int r = 0; r < 4; ++r) {
            size_t row_g = (size_t)b * SEQ + q0 + mt * 16 + quad * 4 + r;
            out[row_g * 128 + n] = c[r] + bias + x[row_g * 128 + n];
        }
    }
}

extern "C" void kernel_launch(void* const* d_in, const int* in_sizes, int n_in,
                              void* d_out, int out_size, void* d_ws, size_t ws_size,
                              hipStream_t stream) {
    const float* x     = (const float*)d_in[0];
    const float* Wq    = (const float*)d_in[1];
    const float* bq    = (const float*)d_in[2];
    const float* Wk    = (const float*)d_in[3];
    const float* bk    = (const float*)d_in[4];
    const float* Wv    = (const float*)d_in[5];
    const float* bv    = (const float*)d_in[6];
    const float* gamma = (const float*)d_in[7];
    const float* beta  = (const float*)d_in[8];
    const float* Wo    = (const float*)d_in[9];
    const float* bo    = (const float*)d_in[10];
    float* out = (float*)d_out;

    const size_t QKV_ELEMS = (size_t)BHN * SEQ * DH;  // 1M
    unsigned short* qf_ws = (unsigned short*)d_ws;
    unsigned short* kf_ws = qf_ws + QKV_ELEMS;
    unsigned short* vf_ws = kf_ws + QKV_ELEMS;
    unsigned short* wf    = vf_ws + QKV_ELEMS;        // 512*128 bf16 frag-major

    k0_prep<<<32, 256, 0, stream>>>(Wq, Wk, Wv, Wo, wf);
    k1_ln_qkv<<<512, 256, 0, stream>>>(x, wf, bq, bk, bv, gamma, beta,
                                       qf_ws, kf_ws, vf_ws);
    k23_attn_out<<<dim3(64, 4), 1024, 0, stream>>>(qf_ws, kf_ws, vf_ws, wf,
                                                   bo, x, out);
}

// Round 8
// 102.494 us; speedup vs baseline: 1.7452x; 1.0037x over previous
//
#include <hip/hip_runtime.h>

#define D_MODEL 128
#define SEQ 2048
#define NH 4
#define DH 32
#define NBATCH 4
#define BHN 16

typedef __attribute__((ext_vector_type(8))) short bf16x8;
typedef __attribute__((ext_vector_type(4))) float f32x4;
typedef __attribute__((ext_vector_type(4))) unsigned short u16x4;
typedef __attribute__((ext_vector_type(8))) unsigned short u16x8;

#define QSCALE (0.17677669529663687f * 1.4426950408889634f)  // log2e/sqrt(32)

static __device__ __forceinline__ unsigned short f2bf_rne(float f) {
    union { float f; unsigned int u; } v; v.f = f;
    unsigned int r = v.u + 0x7FFFu + ((v.u >> 16) & 1u);
    return (unsigned short)(r >> 16);
}

// ======================= Fragment-major layouts ==========================
// Weights wf: 32 n-tiles (q:0-7, k:8-15, v:16-23, o:24-31) x 4 kk x 64 lanes
//   x 8 elems.  B-frag: B[k=kk*32+quad*8+j][n=nt*16+col], lane=quad*16+col.
// Q  qf_ws: [bh][qi(128)][lane][8]   A-frag: Q[qi*16+col][quad*8+j]
// K  kf_ws: [bh][kbi(64)][f(2)][lane][8]  f=0: even keys kb+2*col, f=1: odd.
// V  vf_ws: [bh][kbi(64)][f(2)][lane][8]  B-frag: V[kb+quad*8+j][d], f=0:
//   d=col, f=1: d=col+16.

// ---- k0: weights -> bf16 fragment-major
__global__ __launch_bounds__(256) void k0_prep(
    const float* __restrict__ Wq, const float* __restrict__ Wk,
    const float* __restrict__ Wv, const float* __restrict__ Wo,
    unsigned short* __restrict__ wf)
{
    int tid = blockIdx.x * 256 + threadIdx.x;   // 0..8191
    int nt = tid >> 8, kk = (tid >> 6) & 3, lane = tid & 63;
    int col = lane & 15, quad = lane >> 4;
    const float* W = (nt < 8) ? Wq : (nt < 16) ? Wk : (nt < 24) ? Wv : Wo;
    int n = (nt & 7) * 16 + col;
    u16x8 v;
    #pragma unroll
    for (int j = 0; j < 8; ++j)
        v[j] = f2bf_rne(W[(kk * 32 + quad * 8 + j) * 128 + n]);
    *(u16x8*)(wf + (size_t)tid * 8) = v;
}

// ---- k1: LayerNorm -> bf16 -> MFMA QKV -> LDS repack -> WIDE frag stores.
// 256 blocks x 512 threads (8 waves), block = 32 rows = one 32-key block.
// GEMM: wave = (mt = w&1 row-half, ntgroup = w>>1 -> 6 n-tiles). Results are
// staged in LDS (stqk[s][n] for Q/K, stv[dh][s] for V), then each wave does
// 3 ds_read_b128 + 3 global_store_dwordx4 (one Q, one K, one V frag unit) —
// replacing R7's 48 scalar 2B global scatter-stores per wave.
__global__ __launch_bounds__(512) void k1_ln_qkv(
    const float* __restrict__ x, const unsigned short* __restrict__ wf,
    const float* __restrict__ bq, const float* __restrict__ bk,
    const float* __restrict__ bv,
    const float* __restrict__ gamma, const float* __restrict__ beta,
    unsigned short* __restrict__ qf_ws, unsigned short* __restrict__ kf_ws,
    unsigned short* __restrict__ vf_ws)
{
    __shared__ __align__(16) unsigned short xsh[32][136];    // 8.7 KB
    __shared__ __align__(16) unsigned short stqk[32][272];   // 17.4 KB [s][n 0..255]
    __shared__ __align__(16) unsigned short stv[128][40];    // 10.2 KB [dh][s]
    const int t = threadIdx.x, w = t >> 6, lane = t & 63;
    const int row0 = blockIdx.x * 32;
    const float g0 = gamma[lane], g1 = gamma[lane + 64];
    const float be0 = beta[lane], be1 = beta[lane + 64];
    #pragma unroll
    for (int i = 0; i < 4; ++i) {
        int r = w * 4 + i;
        const float* xr = x + (size_t)(row0 + r) * 128;
        float x0 = xr[lane], x1 = xr[lane + 64];
        float s = x0 + x1, s2 = x0 * x0 + x1 * x1;
        #pragma unroll
        for (int off = 32; off > 0; off >>= 1) {
            s += __shfl_xor(s, off);
            s2 += __shfl_xor(s2, off);
        }
        float mu  = s * (1.0f / 128.0f);
        float var = s2 * (1.0f / 128.0f) - mu * mu;
        float rs  = rsqrtf(var + 1e-6f);
        xsh[r][lane]      = f2bf_rne((x0 - mu) * rs * g0 + be0);
        xsh[r][lane + 64] = f2bf_rne((x1 - mu) * rs * g1 + be1);
    }
    __syncthreads();

    const int col = lane & 15, quad = lane >> 4;
    const int mt = w & 1, mrow = mt * 16;
    const int nt0 = (w >> 1) * 6;
    bf16x8 a[4];
    #pragma unroll
    for (int kk = 0; kk < 4; ++kk)
        a[kk] = *(const bf16x8*)&xsh[mrow + col][kk * 32 + quad * 8];

    for (int nt = nt0; nt < nt0 + 6; ++nt) {
        int n = nt * 16 + col;
        const unsigned short* wrow = wf + (size_t)(nt * 4) * 512 + lane * 8;
        f32x4 c = {0.f, 0.f, 0.f, 0.f};
        #pragma unroll
        for (int kk = 0; kk < 4; ++kk) {
            bf16x8 bfr = *(const bf16x8*)(wrow + kk * 512);
            c = __builtin_amdgcn_mfma_f32_16x16x32_bf16(a[kk], bfr, c, 0, 0, 0);
        }
        int m = nt >> 3;                 // 0=q 1=k 2=v (wave-uniform)
        int nn = n & 127;
        if (m < 2) {
            float bias = (m == 0) ? bq[nn] : bk[nn];
            float scale = (m == 0) ? QSCALE : 1.0f;
            #pragma unroll
            for (int r = 0; r < 4; ++r)
                stqk[mrow + quad * 4 + r][n] = f2bf_rne((c[r] + bias) * scale);
        } else {
            float bias = bv[nn];
            u16x4 pv;
            #pragma unroll
            for (int r = 0; r < 4; ++r) pv[r] = f2bf_rne(c[r] + bias);
            *(u16x4*)&stv[nn][mrow + quad * 4] = pv;   // 8B LDS write
        }
    }
    __syncthreads();

    // ---- wide read+store phase: wave w -> (h = w>>1, par = w&1) ----
    const int b   = row0 >> 11;
    const int kbi = (row0 & (SEQ - 1)) >> 5;
    const int h   = w >> 1, par = w & 1;
    const int bh  = b * NH + h;
    {   // Q unit: qi tile = par
        u16x8 qv = *(const u16x8*)&stqk[par * 16 + col][h * 32 + quad * 8];
        int qi = ((row0 & (SEQ - 1)) >> 4) + par;
        *(u16x8*)(qf_ws + (size_t)(bh * 128 + qi) * 512 + lane * 8) = qv;
    }
    {   // K unit: f = par; lane holds K[kb + 2col+f][quad*8+j]
        u16x8 kv = *(const u16x8*)&stqk[2 * col + par][128 + h * 32 + quad * 8];
        *(u16x8*)(kf_ws + ((size_t)(bh * 64 + kbi) * 2 + par) * 512 + lane * 8) = kv;
    }
    {   // V unit: f = par; lane holds V[kb + quad*8+j][par*16+col]
        u16x8 vv = *(const u16x8*)&stv[h * 32 + par * 16 + col][quad * 8];
        *(u16x8*)(vf_ws + ((size_t)(bh * 64 + kbi) * 2 + par) * 512 + lane * 8) = vv;
    }
}

// ---- k23: attention + out-projection + residual, fused. 16 waves.
// grid (64, 4) = 256 blocks x 1024 threads. Block = 32 queries of batch b,
// ALL 4 heads. Wave w = (head = w>>2, key-quarter kh = w&3), 16 iters.
__global__ __launch_bounds__(1024) void k23_attn_out(
    const unsigned short* __restrict__ qf_ws,
    const unsigned short* __restrict__ kf_ws,
    const unsigned short* __restrict__ vf_ws,
    const unsigned short* __restrict__ wf,
    const float* __restrict__ bo, const float* __restrict__ x,
    float* __restrict__ out)
{
    __shared__ __align__(16) unsigned int p_sh[16][32][36];   // 73.7 KB
    __shared__ __align__(16) float comb[16][32][33];          // 67.6 KB
    __shared__ float lsh[16][32];                             // 2 KB
    __shared__ __align__(16) unsigned short ctx_sh[32][136];  // 8.7 KB

    const int w = threadIdx.x >> 6, lane = threadIdx.x & 63;
    const int col = lane & 15, quad = lane >> 4;
    const int h = w >> 2, kh = w & 3;
    const int b = blockIdx.y;
    const int bh = b * NH + h;
    const int q0 = blockIdx.x * 32;              // block's first q row
    const int qi = blockIdx.x * 2;               // 16-row q tile index

    const unsigned short* qb = qf_ws + (size_t)(bh * 128 + qi) * 512;
    const unsigned short* kb0 = kf_ws + (size_t)bh * 65536 + (size_t)(kh * 16) * 1024;
    const unsigned short* vb0 = vf_ws + (size_t)bh * 65536 + (size_t)(kh * 16) * 1024;

    bf16x8 qf0 = *(const bf16x8*)(qb + lane * 8);
    bf16x8 qf1 = *(const bf16x8*)(qb + 512 + lane * 8);

    f32x4 c00 = {0.f,0.f,0.f,0.f}, c01 = {0.f,0.f,0.f,0.f};
    f32x4 c10 = {0.f,0.f,0.f,0.f}, c11 = {0.f,0.f,0.f,0.f};
    float l0[4] = {0.f,0.f,0.f,0.f}, l1[4] = {0.f,0.f,0.f,0.f};

    const unsigned short* pk = kb0;
    const unsigned short* pv = vb0;
    bf16x8 kf0 = *(const bf16x8*)(pk + lane * 8);
    bf16x8 kf1 = *(const bf16x8*)(pk + 512 + lane * 8);
    bf16x8 vf0 = *(const bf16x8*)(pv + lane * 8);
    bf16x8 vf1 = *(const bf16x8*)(pv + 512 + lane * 8);

    for (int it = 0; it < 16; ++it) {
        const unsigned short* nk = (it == 15) ? kb0 : pk + 1024;
        const unsigned short* nv = (it == 15) ? vb0 : pv + 1024;
        bf16x8 nkf0 = *(const bf16x8*)(nk + lane * 8);
        bf16x8 nkf1 = *(const bf16x8*)(nk + 512 + lane * 8);
        bf16x8 nvf0 = *(const bf16x8*)(nv + lane * 8);
        bf16x8 nvf1 = *(const bf16x8*)(nv + 512 + lane * 8);

        f32x4 z = {0.f,0.f,0.f,0.f};
        f32x4 s00 = __builtin_amdgcn_mfma_f32_16x16x32_bf16(qf0, kf0, z, 0, 0, 0);
        f32x4 s01 = __builtin_amdgcn_mfma_f32_16x16x32_bf16(qf0, kf1, z, 0, 0, 0);
        f32x4 s10 = __builtin_amdgcn_mfma_f32_16x16x32_bf16(qf1, kf0, z, 0, 0, 0);
        f32x4 s11 = __builtin_amdgcn_mfma_f32_16x16x32_bf16(qf1, kf1, z, 0, 0, 0);
        #pragma unroll
        for (int r = 0; r < 4; ++r) {
            float p00 = __builtin_amdgcn_exp2f(s00[r]);
            float p01 = __builtin_amdgcn_exp2f(s01[r]);
            l0[r] += p00 + p01;
            p_sh[w][quad * 4 + r][col] =
                (__float_as_uint(p00) >> 16) | (__float_as_uint(p01) & 0xFFFF0000u);
            float p10 = __builtin_amdgcn_exp2f(s10[r]);
            float p11 = __builtin_amdgcn_exp2f(s11[r]);
            l1[r] += p10 + p11;
            p_sh[w][16 + quad * 4 + r][col] =
                (__float_as_uint(p10) >> 16) | (__float_as_uint(p11) & 0xFFFF0000u);
        }
        bf16x8 pf0 = *(const bf16x8*)&p_sh[w][col][quad * 4];
        bf16x8 pf1 = *(const bf16x8*)&p_sh[w][16 + col][quad * 4];
        c00 = __builtin_amdgcn_mfma_f32_16x16x32_bf16(pf0, vf0, c00, 0, 0, 0);
        c01 = __builtin_amdgcn_mfma_f32_16x16x32_bf16(pf0, vf1, c01, 0, 0, 0);
        c10 = __builtin_amdgcn_mfma_f32_16x16x32_bf16(pf1, vf0, c10, 0, 0, 0);
        c11 = __builtin_amdgcn_mfma_f32_16x16x32_bf16(pf1, vf1, c11, 0, 0, 0);
        kf0 = nkf0; kf1 = nkf1; vf0 = nvf0; vf1 = nvf1;
        pk = nk; pv = nv;
    }

    #pragma unroll
    for (int r = 0; r < 4; ++r) {
        #pragma unroll
        for (int off = 1; off < 16; off <<= 1) {
            l0[r] += __shfl_xor(l0[r], off);
            l1[r] += __shfl_xor(l1[r], off);
        }
    }
    #pragma unroll
    for (int r = 0; r < 4; ++r) {
        int rr = quad * 4 + r;
        comb[w][rr][col]           = c00[r];
        comb[w][rr][16 + col]      = c01[r];
        comb[w][16 + rr][col]      = c10[r];
        comb[w][16 + rr][16 + col] = c11[r];
    }
    if (col == 0) {
        #pragma unroll
        for (int r = 0; r < 4; ++r) {
            lsh[w][quad * 4 + r]      = l0[r];
            lsh[w][16 + quad * 4 + r] = l1[r];
        }
    }
    __syncthreads();

    // combine 4 key-quarters, normalize, store bf16 ctx_sh[32 rows][128 d]
    {
        int row = threadIdx.x >> 5;          // 0..31
        int dg  = (threadIdx.x & 31) * 4;    // 4-col group
        int hh  = dg >> 5;                   // head of this col group
        int wb  = hh * 4;
        float linv = 1.0f / (lsh[wb][row] + lsh[wb + 1][row]
                           + lsh[wb + 2][row] + lsh[wb + 3][row]);
        int dl = dg & 31;
        u16x4 ov;
        #pragma unroll
        for (int j = 0; j < 4; ++j)
            ov[j] = f2bf_rne((comb[wb][row][dl + j] + comb[wb + 1][row][dl + j]
                            + comb[wb + 2][row][dl + j] + comb[wb + 3][row][dl + j])
                             * linv);
        *(u16x4*)&ctx_sh[row][dg] = ov;
    }
    __syncthreads();

    // out-projection: 16 waves <-> 16 (n-tile, m-tile) units
    {
        int nt = w & 7, mt = w >> 3;
        bf16x8 a[4];
        #pragma unroll
        for (int kk = 0; kk < 4; ++kk)
            a[kk] = *(const bf16x8*)&ctx_sh[mt * 16 + col][kk * 32 + quad * 8];
        int n = nt * 16 + col;
        int nt_g = 24 + nt;
        f32x4 c = {0.f, 0.f, 0.f, 0.f};
        #pragma unroll
        for (int kk = 0; kk < 4; ++kk) {
            bf16x8 bfr = *(const bf16x8*)(wf + ((size_t)(nt_g * 4 + kk) * 64 + lane) * 8);
            c = __builtin_amdgcn_mfma_f32_16x16x32_bf16(a[kk], bfr, c, 0, 0, 0);
        }
        float bias = bo[n];
        #pragma unroll
        for (int r = 0; r < 4; ++r) {
            size_t row_g = (size_t)b * SEQ + q0 + mt * 16 + quad * 4 + r;
            out[row_g * 128 + n] = c[r] + bias + x[row_g * 128 + n];
        }
    }
}

extern "C" void kernel_launch(void* const* d_in, const int* in_sizes, int n_in,
                              void* d_out, int out_size, void* d_ws, size_t ws_size,
                              hipStream_t stream) {
    const float* x     = (const float*)d_in[0];
    const float* Wq    = (const float*)d_in[1];
    const float* bq    = (const float*)d_in[2];
    const float* Wk    = (const float*)d_in[3];
    const float* bk    = (const float*)d_in[4];
    const float* Wv    = (const float*)d_in[5];
    const float* bv    = (const float*)d_in[6];
    const float* gamma = (const float*)d_in[7];
    const float* beta  = (const float*)d_in[8];
    const float* Wo    = (const float*)d_in[9];
    const float* bo    = (const float*)d_in[10];
    float* out = (float*)d_out;

    const size_t QKV_ELEMS = (size_t)BHN * SEQ * DH;  // 1M
    unsigned short* qf_ws = (unsigned short*)d_ws;
    unsigned short* kf_ws = qf_ws + QKV_ELEMS;
    unsigned short* vf_ws = kf_ws + QKV_ELEMS;
    unsigned short* wf    = vf_ws + QKV_ELEMS;        // 512*128 bf16 frag-major

    k0_prep<<<32, 256, 0, stream>>>(Wq, Wk, Wv, Wo, wf);
    k1_ln_qkv<<<256, 512, 0, stream>>>(x, wf, bq, bk, bv, gamma, beta,
                                       qf_ws, kf_ws, vf_ws);
    k23_attn_out<<<dim3(64, 4), 1024, 0, stream>>>(qf_ws, kf_ws, vf_ws, wf,
                                                   bo, x, out);
}